// Round 8
// baseline (414.255 us; speedup 1.0000x reference)
//
#include <hip/hip_runtime.h>
#include <math.h>

// B=4, S=2048, F=8, D=256, H=8, L=2, FF=1024, NSK=2000
#define SEQ   2048
#define BATCH 4
#define NTOK  8192
#define DM    256
#define NHD   8
#define DHD   32
#define DFF   1024
#define NSKC  2000

typedef __attribute__((ext_vector_type(8))) short short8;
typedef __attribute__((ext_vector_type(4))) float f32x4;
typedef unsigned short ushort_t;

// 1/sqrt(32) * log2(e): folded into Q so scores come out in exp2 domain.
#define QPRE ((float)(0.17677669529663687 * 1.4426950408889634))

// pair-interleave permutation within each 32-element block
#define SPERM(i) (((i) & ~31) | (((i) & 15) << 1) | (((i) >> 4) & 1))

__device__ __forceinline__ ushort_t f2bf(float x) {
    union { float f; unsigned u; } c; c.f = x;
    unsigned r = c.u + 0x7FFFu + ((c.u >> 16) & 1u);
    return (ushort_t)(r >> 16);
}

#if __has_builtin(__builtin_amdgcn_cvt_pk_bf16_f32)
typedef __attribute__((ext_vector_type(2))) __bf16 bf16x2_t;
__device__ __forceinline__ unsigned pack_bf16(float a, float b) {
    bf16x2_t r = __builtin_amdgcn_cvt_pk_bf16_f32(a, b);
    union { bf16x2_t v; unsigned u; } c; c.v = r;
    return c.u;
}
#else
__device__ __forceinline__ unsigned pack_bf16(float a, float b) {
    return (unsigned)f2bf(a) | ((unsigned)f2bf(b) << 16);
}
#endif

#if __has_builtin(__builtin_amdgcn_exp2f)
__device__ __forceinline__ float fexp2(float x) { return __builtin_amdgcn_exp2f(x); }
#else
__device__ __forceinline__ float fexp2(float x) { return exp2f(x); }
#endif

__device__ __forceinline__ float bf2f(ushort_t x) {
    union { unsigned u; float f; } c; c.u = ((unsigned)x) << 16;
    return c.f;
}

__device__ __forceinline__ float bf2f_lo(unsigned w) {
    union { unsigned u; float f; } c; c.u = w << 16;
    return c.f;
}
__device__ __forceinline__ float bf2f_hi(unsigned w) {
    union { unsigned u; float f; } c; c.u = w & 0xFFFF0000u;
    return c.f;
}

__device__ __forceinline__ short8 mk_s8(unsigned a, unsigned b, unsigned c, unsigned d) {
    union { unsigned u[4]; short8 s; } t;
    t.u[0] = a; t.u[1] = b; t.u[2] = c; t.u[3] = d;
    return t.s;
}

// ---------------------------------------------------------------------------
// Weight conversion, exact tile grid: dst[n][kperm(k)] = bf16(src[k][n]).
// ---------------------------------------------------------------------------
struct ConvSeg { const float* src; ushort_t* dst; int K; int N; int ntx; int base; int kperm; };
struct ConvArgs { ConvSeg s[14]; };

__global__ __launch_bounds__(256) void convert_kernel(ConvArgs args) {
    int bid = blockIdx.x;
    int si = 0;
#pragma unroll
    for (int i = 1; i < 14; i++) if (bid >= args.s[i].base) si = i;
    ConvSeg sg = args.s[si];
    int local = bid - sg.base;
    int ty = local / sg.ntx;
    int tx = local - ty * sg.ntx;
    int n0 = tx * 32, k0 = ty * 32;
    __shared__ float T[32][33];
    int tid = threadIdx.x;
    int tn = tid & 31, tk4 = tid >> 5;
#pragma unroll
    for (int i = 0; i < 4; i++) {
        int kl = tk4 + i * 8;
        float v = 0.0f;
        if (n0 + tn < sg.N) v = sg.src[(size_t)(k0 + kl) * sg.N + n0 + tn];
        T[kl][tn] = v;
    }
    __syncthreads();
    int tk = tid & 31, tn4 = tid >> 5;
    int tks = sg.kperm ? (((tk & 15) << 1) | ((tk >> 4) & 1)) : tk;
#pragma unroll
    for (int i = 0; i < 4; i++) {
        int nl = tn4 + i * 8;
        sg.dst[(size_t)(n0 + nl) * sg.K + k0 + tks] = f2bf(T[tk][nl]);
    }
}

// ---------------------------------------------------------------------------
// concat row [inter_e(256) | pat_e(64) | feat_e(64)] -> bf16 (plain layout)
// ---------------------------------------------------------------------------
__global__ __launch_bounds__(384) void concat_kernel(
    const int* __restrict__ interactions, const int* __restrict__ patterns,
    const float* __restrict__ ff, const float* __restrict__ inter_emb,
    const float* __restrict__ pattern_emb, const float* __restrict__ feat_W,
    const float* __restrict__ feat_b, ushort_t* __restrict__ out)
{
    int tok = blockIdx.x;
    int j = threadIdx.x;
    float v;
    if (j < 256) {
        v = inter_emb[(size_t)interactions[tok] * 256 + j];
    } else if (j < 320) {
        v = pattern_emb[patterns[tok] * 64 + (j - 256)];
    } else {
        int c = j - 320;
        float acc = feat_b[c];
#pragma unroll
        for (int f = 0; f < 8; f++) acc += ff[tok * 8 + f] * feat_W[f * 64 + c];
        v = acc;
    }
    out[(size_t)tok * 384 + j] = f2bf(v);
}

// ---------------------------------------------------------------------------
// ln_kernel v2 (vectorized): LayerNorm(x + r) in place. 16 rows/block.
// ---------------------------------------------------------------------------
__global__ __launch_bounds__(256) void ln_kernel(
    float* __restrict__ x, const ushort_t* __restrict__ r,
    const float* __restrict__ g, const float* __restrict__ b,
    ushort_t* __restrict__ xb)
{
    int t = threadIdx.x;
    int row = blockIdx.x * 16 + (t >> 4);
    int k = t & 15;
    int d0 = (k >> 1) * 32 + (k & 1) * 8;   // lower 8 at d0.., upper 8 at d0+16..
    int p0 = (k >> 1) * 32 + (k & 1) * 16;  // permuted byte-pair base
    size_t rowb = (size_t)row * DM;

    float4 xl0 = *(const float4*)&x[rowb + d0];
    float4 xl1 = *(const float4*)&x[rowb + d0 + 4];
    float4 xh0 = *(const float4*)&x[rowb + d0 + 16];
    float4 xh1 = *(const float4*)&x[rowb + d0 + 20];
    uint4 r0 = *(const uint4*)&r[rowb + p0];
    uint4 r1 = *(const uint4*)&r[rowb + p0 + 8];

    float vlo[8], vhi[8];
    unsigned rw[8] = {r0.x, r0.y, r0.z, r0.w, r1.x, r1.y, r1.z, r1.w};
    const float* xlp0 = (const float*)&xl0;
    const float* xlp1 = (const float*)&xl1;
    const float* xhp0 = (const float*)&xh0;
    const float* xhp1 = (const float*)&xh1;
#pragma unroll
    for (int i = 0; i < 4; i++) {
        vlo[i]     = xlp0[i] + bf2f_lo(rw[i]);
        vlo[4 + i] = xlp1[i] + bf2f_lo(rw[4 + i]);
        vhi[i]     = xhp0[i] + bf2f_hi(rw[i]);
        vhi[4 + i] = xhp1[i] + bf2f_hi(rw[4 + i]);
    }

    float s1 = 0.f, s2 = 0.f;
#pragma unroll
    for (int i = 0; i < 8; i++) {
        s1 += vlo[i] + vhi[i];
        s2 += vlo[i] * vlo[i] + vhi[i] * vhi[i];
    }
#pragma unroll
    for (int off = 1; off < 16; off <<= 1) {
        s1 += __shfl_xor(s1, off, 16);
        s2 += __shfl_xor(s2, off, 16);
    }
    float mean = s1 * (1.0f / 256.0f);
    float var = s2 * (1.0f / 256.0f) - mean * mean;
    float inv = rsqrtf(var + 1e-6f);

    float4 gl0 = *(const float4*)&g[d0];
    float4 gl1 = *(const float4*)&g[d0 + 4];
    float4 gh0 = *(const float4*)&g[d0 + 16];
    float4 gh1 = *(const float4*)&g[d0 + 20];
    float4 bl0 = *(const float4*)&b[d0];
    float4 bl1 = *(const float4*)&b[d0 + 4];
    float4 bh0 = *(const float4*)&b[d0 + 16];
    float4 bh1 = *(const float4*)&b[d0 + 20];
    const float* glp0 = (const float*)&gl0; const float* glp1 = (const float*)&gl1;
    const float* ghp0 = (const float*)&gh0; const float* ghp1 = (const float*)&gh1;
    const float* blp0 = (const float*)&bl0; const float* blp1 = (const float*)&bl1;
    const float* bhp0 = (const float*)&bh0; const float* bhp1 = (const float*)&bh1;

    float nlo[8], nhi[8];
#pragma unroll
    for (int i = 0; i < 4; i++) {
        nlo[i]     = glp0[i] * (vlo[i] - mean) * inv + blp0[i];
        nlo[4 + i] = glp1[i] * (vlo[4 + i] - mean) * inv + blp1[i];
        nhi[i]     = ghp0[i] * (vhi[i] - mean) * inv + bhp0[i];
        nhi[4 + i] = ghp1[i] * (vhi[4 + i] - mean) * inv + bhp1[i];
    }

    *(float4*)&x[rowb + d0]      = (float4){nlo[0], nlo[1], nlo[2], nlo[3]};
    *(float4*)&x[rowb + d0 + 4]  = (float4){nlo[4], nlo[5], nlo[6], nlo[7]};
    *(float4*)&x[rowb + d0 + 16] = (float4){nhi[0], nhi[1], nhi[2], nhi[3]};
    *(float4*)&x[rowb + d0 + 20] = (float4){nhi[4], nhi[5], nhi[6], nhi[7]};
    uint4 o0, o1;
    o0.x = pack_bf16(nlo[0], nhi[0]); o0.y = pack_bf16(nlo[1], nhi[1]);
    o0.z = pack_bf16(nlo[2], nhi[2]); o0.w = pack_bf16(nlo[3], nhi[3]);
    o1.x = pack_bf16(nlo[4], nhi[4]); o1.y = pack_bf16(nlo[5], nhi[5]);
    o1.z = pack_bf16(nlo[6], nhi[6]); o1.w = pack_bf16(nlo[7], nhi[7]);
    *(uint4*)&xb[rowb + p0]     = o0;
    *(uint4*)&xb[rowb + p0 + 8] = o1;
}

// ---------------------------------------------------------------------------
// gemm_inproj: gemm64 geometry (BM=64 BN=64 BK=32, 4 waves x 16x64),
// mode-4 epilogue hardcoded.
// ---------------------------------------------------------------------------
__global__ __launch_bounds__(256) void gemm_inproj(
    const ushort_t* __restrict__ A, const ushort_t* __restrict__ Bt,
    int N, int K,
    float* __restrict__ Cf, ushort_t* __restrict__ Cb,
    const float* __restrict__ b0,
    const float* __restrict__ ffg, const float* __restrict__ tW,
    const float* __restrict__ tb, const float* __restrict__ pW,
    const float* __restrict__ pb)
{
    __shared__ ushort_t As[2][64][40];
    __shared__ ushort_t Bs[2][64][40];
    int m0 = blockIdx.x * 64, n0 = blockIdx.y * 64;
    int tid = threadIdx.x;
    int wv = tid >> 6, lane = tid & 63;
    int quad = lane >> 4, l16 = lane & 15;
    int srow = tid >> 2, sc = (tid & 3) << 3;

    f32x4 acc[4];
#pragma unroll
    for (int j = 0; j < 4; j++) acc[j] = (f32x4){0.f, 0.f, 0.f, 0.f};

    uint4 pa = *(const uint4*)&A[(size_t)(m0 + srow) * K + sc];
    uint4 pbv = *(const uint4*)&Bt[(size_t)(n0 + srow) * K + sc];
    *(uint4*)&As[0][srow][sc] = pa;
    *(uint4*)&Bs[0][srow][sc] = pbv;

    int mrow = wv * 16;
    for (int k0 = 0; k0 < K; k0 += 32) {
        int cur = (k0 >> 5) & 1;
        __syncthreads();
        bool more = (k0 + 32 < K);
        if (more) {
            pa = *(const uint4*)&A[(size_t)(m0 + srow) * K + k0 + 32 + sc];
            pbv = *(const uint4*)&Bt[(size_t)(n0 + srow) * K + k0 + 32 + sc];
        }
        short8 af = *(const short8*)&As[cur][mrow + l16][quad * 8];
        short8 bf0 = *(const short8*)&Bs[cur][l16][quad * 8];
        short8 bf1 = *(const short8*)&Bs[cur][16 + l16][quad * 8];
        short8 bf2 = *(const short8*)&Bs[cur][32 + l16][quad * 8];
        short8 bf3 = *(const short8*)&Bs[cur][48 + l16][quad * 8];
        acc[0] = __builtin_amdgcn_mfma_f32_16x16x32_bf16(af, bf0, acc[0], 0, 0, 0);
        acc[1] = __builtin_amdgcn_mfma_f32_16x16x32_bf16(af, bf1, acc[1], 0, 0, 0);
        acc[2] = __builtin_amdgcn_mfma_f32_16x16x32_bf16(af, bf2, acc[2], 0, 0, 0);
        acc[3] = __builtin_amdgcn_mfma_f32_16x16x32_bf16(af, bf3, acc[3], 0, 0, 0);
        if (more) {
            *(uint4*)&As[cur ^ 1][srow][sc] = pa;
            *(uint4*)&Bs[cur ^ 1][srow][sc] = pbv;
        }
    }

#pragma unroll
    for (int r = 0; r < 4; r++) {
        int m = m0 + mrow + quad * 4 + r;
        int s = m & (SEQ - 1);
        float el = ffg[m * 8];
        float pos = (float)s * (1.0f / (float)SEQ);
#pragma unroll
        for (int nt = 0; nt < 4; nt += 2) {
            int nlo = n0 + nt * 16 + l16;
            int nhi = nlo + 16;
            float v0 = acc[nt][r] + b0[nlo] + tanhf(el * tW[nlo] + tb[nlo]) + pos * pW[nlo] + pb[nlo];
            float v1 = acc[nt + 1][r] + b0[nhi] + tanhf(el * tW[nhi] + tb[nhi]) + pos * pW[nhi] + pb[nhi];
            Cf[(size_t)m * N + nlo] = v0;
            Cf[(size_t)m * N + nhi] = v1;
            *(unsigned*)&Cb[(size_t)m * N + n0 + nt * 16 + 2 * l16] = pack_bf16(v0, v1);
        }
    }
}

// ---------------------------------------------------------------------------
// gemm_wo: gemm64 geometry, mode-5 epilogue hardcoded.
// ---------------------------------------------------------------------------
__global__ __launch_bounds__(256) void gemm_wo(
    const ushort_t* __restrict__ A, const ushort_t* __restrict__ Bt,
    int N, int K,
    ushort_t* __restrict__ Cb, const float* __restrict__ b0)
{
    __shared__ ushort_t As[2][64][40];
    __shared__ ushort_t Bs[2][64][40];
    int m0 = blockIdx.x * 64, n0 = blockIdx.y * 64;
    int tid = threadIdx.x;
    int wv = tid >> 6, lane = tid & 63;
    int quad = lane >> 4, l16 = lane & 15;
    int srow = tid >> 2, sc = (tid & 3) << 3;

    f32x4 acc[4];
#pragma unroll
    for (int j = 0; j < 4; j++) acc[j] = (f32x4){0.f, 0.f, 0.f, 0.f};

    uint4 pa = *(const uint4*)&A[(size_t)(m0 + srow) * K + sc];
    uint4 pbv = *(const uint4*)&Bt[(size_t)(n0 + srow) * K + sc];
    *(uint4*)&As[0][srow][sc] = pa;
    *(uint4*)&Bs[0][srow][sc] = pbv;

    int mrow = wv * 16;
    for (int k0 = 0; k0 < K; k0 += 32) {
        int cur = (k0 >> 5) & 1;
        __syncthreads();
        bool more = (k0 + 32 < K);
        if (more) {
            pa = *(const uint4*)&A[(size_t)(m0 + srow) * K + k0 + 32 + sc];
            pbv = *(const uint4*)&Bt[(size_t)(n0 + srow) * K + k0 + 32 + sc];
        }
        short8 af = *(const short8*)&As[cur][mrow + l16][quad * 8];
        short8 bf0 = *(const short8*)&Bs[cur][l16][quad * 8];
        short8 bf1 = *(const short8*)&Bs[cur][16 + l16][quad * 8];
        short8 bf2 = *(const short8*)&Bs[cur][32 + l16][quad * 8];
        short8 bf3 = *(const short8*)&Bs[cur][48 + l16][quad * 8];
        acc[0] = __builtin_amdgcn_mfma_f32_16x16x32_bf16(af, bf0, acc[0], 0, 0, 0);
        acc[1] = __builtin_amdgcn_mfma_f32_16x16x32_bf16(af, bf1, acc[1], 0, 0, 0);
        acc[2] = __builtin_amdgcn_mfma_f32_16x16x32_bf16(af, bf2, acc[2], 0, 0, 0);
        acc[3] = __builtin_amdgcn_mfma_f32_16x16x32_bf16(af, bf3, acc[3], 0, 0, 0);
        if (more) {
            *(uint4*)&As[cur ^ 1][srow][sc] = pa;
            *(uint4*)&Bs[cur ^ 1][srow][sc] = pbv;
        }
    }

#pragma unroll
    for (int r = 0; r < 4; r++) {
        int m = m0 + mrow + quad * 4 + r;
#pragma unroll
        for (int nt = 0; nt < 4; nt += 2) {
            int nlo = n0 + nt * 16 + l16;
            float v0 = acc[nt][r] + b0[nlo];
            float v1 = acc[nt + 1][r] + b0[nlo + 16];
            *(unsigned*)&Cb[(size_t)m * N + n0 + nt * 16 + 2 * l16] = pack_bf16(v0, v1);
        }
    }
}

// ---------------------------------------------------------------------------
// gemm_ffn2: gemm_db geometry (BM=128 BN=64, 8 mfma/iter/wave) for FFN2
// (M=8192, N=256, K=1024), bias-only packed-bf16 epilogue. Grid (64,4).
// ---------------------------------------------------------------------------
__global__ __launch_bounds__(256) void gemm_ffn2(
    const ushort_t* __restrict__ A, const ushort_t* __restrict__ Bt,
    int N, int K,
    ushort_t* __restrict__ Cb, const float* __restrict__ b0)
{
    __shared__ ushort_t As[2][128][40];
    __shared__ ushort_t Bs[2][64][40];
    int m0 = blockIdx.x * 128, n0 = blockIdx.y * 64;
    int tid = threadIdx.x;
    int wv = tid >> 6, lane = tid & 63;
    int quad = lane >> 4, l16 = lane & 15;
    int srow = tid >> 2, sc = (tid & 3) << 3;

    f32x4 acc[2][4];
#pragma unroll
    for (int i = 0; i < 2; i++)
#pragma unroll
        for (int j = 0; j < 4; j++) acc[i][j] = (f32x4){0.f, 0.f, 0.f, 0.f};

    uint4 pa0 = *(const uint4*)&A[(size_t)(m0 + srow) * K + sc];
    uint4 pa1 = *(const uint4*)&A[(size_t)(m0 + 64 + srow) * K + sc];
    uint4 pbb = *(const uint4*)&Bt[(size_t)(n0 + srow) * K + sc];
    *(uint4*)&As[0][srow][sc] = pa0;
    *(uint4*)&As[0][64 + srow][sc] = pa1;
    *(uint4*)&Bs[0][srow][sc] = pbb;

    int msub = wv * 32;
    for (int k0 = 0; k0 < K; k0 += 32) {
        int cur = (k0 >> 5) & 1;
        __syncthreads();
        bool more = (k0 + 32 < K);
        if (more) {
            pa0 = *(const uint4*)&A[(size_t)(m0 + srow) * K + k0 + 32 + sc];
            pa1 = *(const uint4*)&A[(size_t)(m0 + 64 + srow) * K + k0 + 32 + sc];
            pbb = *(const uint4*)&Bt[(size_t)(n0 + srow) * K + k0 + 32 + sc];
        }
        short8 af0 = *(const short8*)&As[cur][msub + l16][quad * 8];
        short8 af1 = *(const short8*)&As[cur][msub + 16 + l16][quad * 8];
        short8 bf0 = *(const short8*)&Bs[cur][l16][quad * 8];
        short8 bf1 = *(const short8*)&Bs[cur][16 + l16][quad * 8];
        short8 bf2 = *(const short8*)&Bs[cur][32 + l16][quad * 8];
        short8 bf3 = *(const short8*)&Bs[cur][48 + l16][quad * 8];
        acc[0][0] = __builtin_amdgcn_mfma_f32_16x16x32_bf16(af0, bf0, acc[0][0], 0, 0, 0);
        acc[0][1] = __builtin_amdgcn_mfma_f32_16x16x32_bf16(af0, bf1, acc[0][1], 0, 0, 0);
        acc[0][2] = __builtin_amdgcn_mfma_f32_16x16x32_bf16(af0, bf2, acc[0][2], 0, 0, 0);
        acc[0][3] = __builtin_amdgcn_mfma_f32_16x16x32_bf16(af0, bf3, acc[0][3], 0, 0, 0);
        acc[1][0] = __builtin_amdgcn_mfma_f32_16x16x32_bf16(af1, bf0, acc[1][0], 0, 0, 0);
        acc[1][1] = __builtin_amdgcn_mfma_f32_16x16x32_bf16(af1, bf1, acc[1][1], 0, 0, 0);
        acc[1][2] = __builtin_amdgcn_mfma_f32_16x16x32_bf16(af1, bf2, acc[1][2], 0, 0, 0);
        acc[1][3] = __builtin_amdgcn_mfma_f32_16x16x32_bf16(af1, bf3, acc[1][3], 0, 0, 0);
        if (more) {
            *(uint4*)&As[cur ^ 1][srow][sc] = pa0;
            *(uint4*)&As[cur ^ 1][64 + srow][sc] = pa1;
            *(uint4*)&Bs[cur ^ 1][srow][sc] = pbb;
        }
    }

#pragma unroll
    for (int mt = 0; mt < 2; mt++) {
#pragma unroll
        for (int nt = 0; nt < 4; nt += 2) {
            int nlo = n0 + nt * 16 + l16;
#pragma unroll
            for (int r = 0; r < 4; r++) {
                int m = m0 + msub + mt * 16 + quad * 4 + r;
                float t0 = acc[mt][nt][r] + b0[nlo];
                float t1 = acc[mt][nt + 1][r] + b0[nlo + 16];
                *(unsigned*)&Cb[(size_t)m * N + n0 + nt * 16 + 2 * l16] = pack_bf16(t0, t1);
            }
        }
    }
}

// ---------------------------------------------------------------------------
// gemm_db: BM=128 BN=64 BK=32, double-buffered (1 barrier/iter).
// mode 1: gelu -> packed bf16
// mode 2: QKV epilogue
// ---------------------------------------------------------------------------
__global__ __launch_bounds__(256) void gemm_db(
    const ushort_t* __restrict__ A, const ushort_t* __restrict__ Bt,
    int M, int N, int K, int mode,
    ushort_t* __restrict__ Cb, ushort_t* __restrict__ Ck, ushort_t* __restrict__ Cv,
    const float* __restrict__ b0, const float* __restrict__ b1,
    const float* __restrict__ b2)
{
    __shared__ ushort_t As[2][128][40];
    __shared__ ushort_t Bs[2][64][40];
    int m0 = blockIdx.x * 128, n0 = blockIdx.y * 64;
    int tid = threadIdx.x;
    int wv = tid >> 6, lane = tid & 63;
    int quad = lane >> 4, l16 = lane & 15;
    int srow = tid >> 2, sc = (tid & 3) << 3;

    f32x4 acc[2][4];
#pragma unroll
    for (int i = 0; i < 2; i++)
#pragma unroll
        for (int j = 0; j < 4; j++) acc[i][j] = (f32x4){0.f, 0.f, 0.f, 0.f};

    uint4 pa0 = *(const uint4*)&A[(size_t)(m0 + srow) * K + sc];
    uint4 pa1 = *(const uint4*)&A[(size_t)(m0 + 64 + srow) * K + sc];
    uint4 pbb = *(const uint4*)&Bt[(size_t)(n0 + srow) * K + sc];
    *(uint4*)&As[0][srow][sc] = pa0;
    *(uint4*)&As[0][64 + srow][sc] = pa1;
    *(uint4*)&Bs[0][srow][sc] = pbb;

    int msub = wv * 32;
    for (int k0 = 0; k0 < K; k0 += 32) {
        int cur = (k0 >> 5) & 1;
        __syncthreads();
        bool more = (k0 + 32 < K);
        if (more) {
            pa0 = *(const uint4*)&A[(size_t)(m0 + srow) * K + k0 + 32 + sc];
            pa1 = *(const uint4*)&A[(size_t)(m0 + 64 + srow) * K + k0 + 32 + sc];
            pbb = *(const uint4*)&Bt[(size_t)(n0 + srow) * K + k0 + 32 + sc];
        }
        short8 af0 = *(const short8*)&As[cur][msub + l16][quad * 8];
        short8 af1 = *(const short8*)&As[cur][msub + 16 + l16][quad * 8];
        short8 bf0 = *(const short8*)&Bs[cur][l16][quad * 8];
        short8 bf1 = *(const short8*)&Bs[cur][16 + l16][quad * 8];
        short8 bf2 = *(const short8*)&Bs[cur][32 + l16][quad * 8];
        short8 bf3 = *(const short8*)&Bs[cur][48 + l16][quad * 8];
        acc[0][0] = __builtin_amdgcn_mfma_f32_16x16x32_bf16(af0, bf0, acc[0][0], 0, 0, 0);
        acc[0][1] = __builtin_amdgcn_mfma_f32_16x16x32_bf16(af0, bf1, acc[0][1], 0, 0, 0);
        acc[0][2] = __builtin_amdgcn_mfma_f32_16x16x32_bf16(af0, bf2, acc[0][2], 0, 0, 0);
        acc[0][3] = __builtin_amdgcn_mfma_f32_16x16x32_bf16(af0, bf3, acc[0][3], 0, 0, 0);
        acc[1][0] = __builtin_amdgcn_mfma_f32_16x16x32_bf16(af1, bf0, acc[1][0], 0, 0, 0);
        acc[1][1] = __builtin_amdgcn_mfma_f32_16x16x32_bf16(af1, bf1, acc[1][1], 0, 0, 0);
        acc[1][2] = __builtin_amdgcn_mfma_f32_16x16x32_bf16(af1, bf2, acc[1][2], 0, 0, 0);
        acc[1][3] = __builtin_amdgcn_mfma_f32_16x16x32_bf16(af1, bf3, acc[1][3], 0, 0, 0);
        if (more) {
            *(uint4*)&As[cur ^ 1][srow][sc] = pa0;
            *(uint4*)&As[cur ^ 1][64 + srow][sc] = pa1;
            *(uint4*)&Bs[cur ^ 1][srow][sc] = pbb;
        }
    }

#pragma unroll
    for (int mt = 0; mt < 2; mt++) {
#pragma unroll
        for (int nt = 0; nt < 4; nt += 2) {
            int nlo = n0 + nt * 16 + l16;
#pragma unroll
            for (int r = 0; r < 4; r++) {
                int m = m0 + msub + mt * 16 + quad * 4 + r;
                float vlo = acc[mt][nt][r];
                float vhi = acc[mt][nt + 1][r];
                if (mode == 1) {
                    float t0 = vlo + b0[nlo];
                    float t1 = vhi + b0[nlo + 16];
                    t0 = 0.5f * t0 * (1.0f + erff(t0 * 0.70710678118654752f));
                    t1 = 0.5f * t1 * (1.0f + erff(t1 * 0.70710678118654752f));
                    *(unsigned*)&Cb[(size_t)m * N + n0 + nt * 16 + 2 * l16] = pack_bf16(t0, t1);
                } else {
                    int which = nlo >> 8, idx = nlo & 255;
                    int hh = idx >> 5;          // d == l16, partner d+16 same head
                    int s = m & (SEQ - 1), b = m >> 11;
                    if (which == 0) {
                        float q0 = (vlo + b0[idx]) * QPRE;
                        float q1 = (vhi + b0[idx + 16]) * QPRE;
                        *(unsigned*)&Cb[(((size_t)(b * NHD + hh)) * SEQ + s) * DHD + 2 * l16] = pack_bf16(q0, q1);
                    } else if (which == 1) {
                        float k0v = vlo + b1[idx];
                        float k1v = vhi + b1[idx + 16];
                        *(unsigned*)&Ck[(((size_t)(b * NHD + hh)) * SEQ + s) * DHD + 2 * l16] = pack_bf16(k0v, k1v);
                    } else {
                        Cv[(((size_t)(b * NHD + hh)) * DHD + l16) * SEQ + s] = f2bf(vlo + b2[idx]);
                        Cv[(((size_t)(b * NHD + hh)) * DHD + l16 + 16) * SEQ + s] = f2bf(vhi + b2[idx + 16]);
                    }
                }
            }
        }
    }
}

// ---------------------------------------------------------------------------
// gemm_out: BM=128 BN=128 BK=32, double-buffered. fp32 + bias, n < Nreal.
// ---------------------------------------------------------------------------
__global__ __launch_bounds__(256) void gemm_out(
    const ushort_t* __restrict__ A, const ushort_t* __restrict__ Bt,
    int M, int N, int K,
    float* __restrict__ Cf, const float* __restrict__ b0, int Nreal)
{
    __shared__ ushort_t As[2][128][40];
    __shared__ ushort_t Bs[2][128][40];
    int m0 = blockIdx.x * 128, n0 = blockIdx.y * 128;
    int tid = threadIdx.x;
    int wv = tid >> 6, lane = tid & 63;
    int quad = lane >> 4, l16 = lane & 15;
    int wm = (wv >> 1) * 64, wn = (wv & 1) * 64;
    int srow = tid >> 1, sc = (tid & 1) << 4;

    f32x4 acc[4][4];
#pragma unroll
    for (int i = 0; i < 4; i++)
#pragma unroll
        for (int j = 0; j < 4; j++) acc[i][j] = (f32x4){0.f, 0.f, 0.f, 0.f};

    uint4 pa0 = *(const uint4*)&A[(size_t)(m0 + srow) * K + sc];
    uint4 pa1 = *(const uint4*)&A[(size_t)(m0 + srow) * K + sc + 8];
    uint4 pb0 = *(const uint4*)&Bt[(size_t)(n0 + srow) * K + sc];
    uint4 pb1 = *(const uint4*)&Bt[(size_t)(n0 + srow) * K + sc + 8];
    *(uint4*)&As[0][srow][sc] = pa0;
    *(uint4*)&As[0][srow][sc + 8] = pa1;
    *(uint4*)&Bs[0][srow][sc] = pb0;
    *(uint4*)&Bs[0][srow][sc + 8] = pb1;

    for (int k0 = 0; k0 < K; k0 += 32) {
        int cur = (k0 >> 5) & 1;
        __syncthreads();
        bool more = (k0 + 32 < K);
        if (more) {
            pa0 = *(const uint4*)&A[(size_t)(m0 + srow) * K + k0 + 32 + sc];
            pa1 = *(const uint4*)&A[(size_t)(m0 + srow) * K + k0 + 32 + sc + 8];
            pb0 = *(const uint4*)&Bt[(size_t)(n0 + srow) * K + k0 + 32 + sc];
            pb1 = *(const uint4*)&Bt[(size_t)(n0 + srow) * K + k0 + 32 + sc + 8];
        }
        short8 af[4], bf[4];
#pragma unroll
        for (int i = 0; i < 4; i++) {
            af[i] = *(const short8*)&As[cur][wm + i * 16 + l16][quad * 8];
            bf[i] = *(const short8*)&Bs[cur][wn + i * 16 + l16][quad * 8];
        }
#pragma unroll
        for (int i = 0; i < 4; i++)
#pragma unroll
            for (int j = 0; j < 4; j++)
                acc[i][j] = __builtin_amdgcn_mfma_f32_16x16x32_bf16(af[i], bf[j], acc[i][j], 0, 0, 0);
        if (more) {
            *(uint4*)&As[cur ^ 1][srow][sc] = pa0;
            *(uint4*)&As[cur ^ 1][srow][sc + 8] = pa1;
            *(uint4*)&Bs[cur ^ 1][srow][sc] = pb0;
            *(uint4*)&Bs[cur ^ 1][srow][sc + 8] = pb1;
        }
    }

#pragma unroll
    for (int i = 0; i < 4; i++) {
#pragma unroll
        for (int j = 0; j < 4; j++) {
            int n = n0 + wn + j * 16 + l16;
            if (n < Nreal) {
#pragma unroll
                for (int r = 0; r < 4; r++) {
                    int m = m0 + wm + i * 16 + quad * 4 + r;
                    Cf[(size_t)m * Nreal + n] = acc[i][j][r] + b0[n];
                }
            }
        }
    }
}

// ---------------------------------------------------------------------------
// MFMA flash attention v4 (swapped-operand, zero P-LDS) -- proven ~47 us.
// R8: grid split into TWO dispatches of 1024 blocks (gid0 = 0 / 1024) so
// each half is ~24 us -> lowers the rocprof top-5 cutoff and surfaces the
// hidden mid-size kernels. Blocks fully independent; XCD pinning preserved.
// ---------------------------------------------------------------------------
__global__ __launch_bounds__(256) void attn_mfma(
    const ushort_t* __restrict__ qb, const ushort_t* __restrict__ kb,
    const ushort_t* __restrict__ vtb, const float* __restrict__ kp,
    const float* __restrict__ ka, ushort_t* __restrict__ ob, int gid0)
{
    // gid = (hb>>3)*512 + pj*8 + (hb&7)  (bijective over 2048)
    int gid = blockIdx.x + gid0;
    int hb = ((gid >> 9) << 3) | (gid & 7);
    int pj = (gid >> 3) & 63;
    int b = hb >> 3, h = hb & 7;

    int tid = threadIdx.x, wv = tid >> 6, lane = tid & 63;
    int quad = lane >> 4, l16 = lane & 15;

    __shared__ float tabs[2112];
    __shared__ __align__(16) float ShA[2560];   // O-combine, stride 20
    __shared__ float LsB[128];                  // per-wave denominators

    float p = log1pf(__expf(kp[h]));
    float a = log1pf(__expf(ka[h]));
    for (int i = tid; i < 2112; i += 256) {
        float w = 0.0f;
        if (i >= 64) w = fexp2(-p * __log2f(fmaf(a, (float)(i - 64), 1.0f)));
        tabs[i] = w;
    }
    __syncthreads();

    int bh = b * NHD + h;
    const ushort_t* Qh = qb + (size_t)bh * SEQ * DHD;
    const ushort_t* Kh = kb + (size_t)bh * SEQ * DHD;
    const ushort_t* Vh = vtb + (size_t)bh * DHD * SEQ;

    int tlo = pj, thi = 127 - pj;
    int qlo0 = tlo * 16, qhi0 = thi * 16;

    short8 qfl = *(const short8*)&Qh[(qlo0 + l16) * DHD + quad * 8];
    short8 qfh = *(const short8*)&Qh[(qhi0 + l16) * DHD + quad * 8];
    f32x4 ol0 = (f32x4){0.f,0.f,0.f,0.f}, ol1 = (f32x4){0.f,0.f,0.f,0.f};
    f32x4 oh0 = (f32x4){0.f,0.f,0.f,0.f}, oh1 = (f32x4){0.f,0.f,0.f,0.f};
    float lsh_s = 0.f, lsl_s = 0.f;

    int nch_hi = (thi + 2) >> 1;     // >= 33, so every wave gets hi work
    int nch_lo = (tlo + 2) >> 1;     // >= 1
    // permuted K row offset: l16 -> {0-3,8-11,16-19,24-27}
    int krow = ((l16 >> 2) << 3) | (l16 & 3);
    int tb_h = qhi0 + l16 + 64 - 8 * quad;
    int tb_l = qlo0 + l16 + 64 - 8 * quad;

    int ch = wv;
    short8 kf0n, kf1n;
    {
        int k0 = ch * 32;
        kf0n = *(const short8*)&Kh[(k0 + krow) * DHD + quad * 8];
        kf1n = *(const short8*)&Kh[(k0 + 4 + krow) * DHD + quad * 8];
    }

    for (; ch < nch_hi; ch += 4) {
        int k0 = ch * 32;
        short8 kf0 = kf0n, kf1 = kf1n;
        short8 vf0 = *(const short8*)&Vh[l16 * SEQ + k0 + quad * 8];
        short8 vf1 = *(const short8*)&Vh[(16 + l16) * SEQ + k0 + quad * 8];
        int chn = ch + 4;
        if (chn < nch_hi) {
            int kn = chn * 32;
            kf0n = *(const short8*)&Kh[(kn + krow) * DHD + quad * 8];
            kf1n = *(const short8*)&Kh[(kn + 4 + krow) * DHD + quad * 8];
        }
        f32x4 z = (f32x4){0.f,0.f,0.f,0.f};

        // scores: s0[r] = S[k0+8q+r][q=l16], s1[r] = S[k0+8q+4+r][q=l16]
        f32x4 s0 = __builtin_amdgcn_mfma_f32_16x16x32_bf16(kf0, qfh, z, 0, 0, 0);
        f32x4 s1 = __builtin_amdgcn_mfma_f32_16x16x32_bf16(kf1, qfh, z, 0, 0, 0);
        {
            const float* tp = &tabs[tb_h - k0];
            float e0 = fexp2(s0[0]) * tp[0];
            float e1 = fexp2(s0[1]) * tp[-1];
            float e2 = fexp2(s0[2]) * tp[-2];
            float e3 = fexp2(s0[3]) * tp[-3];
            unsigned p0 = pack_bf16(e0, e1);
            unsigned p1 = pack_bf16(e2, e3);
            float f0 = fexp2(s1[0]) * tp[-4];
            float f1 = fexp2(s1[1]) * tp[-5];
            float f2 = fexp2(s1[2]) * tp[-6];
            float f3 = fexp2(s1[3]) * tp[-7];
            unsigned p2 = pack_bf16(f0, f1);
            unsigned p3 = pack_bf16(f2, f3);
            lsh_s += ((e0 + e1) + (e2 + e3)) + ((f0 + f1) + (f2 + f3));
            short8 pf = mk_s8(p0, p1, p2, p3);
            oh0 = __builtin_amdgcn_mfma_f32_16x16x32_bf16(pf, vf0, oh0, 0, 0, 0);
            oh1 = __builtin_amdgcn_mfma_f32_16x16x32_bf16(pf, vf1, oh1, 0, 0, 0);
        }
        if (ch < nch_lo) {
            f32x4 t0 = __builtin_amdgcn_mfma_f32_16x16x32_bf16(kf0, qfl, z, 0, 0, 0);
            f32x4 t1 = __builtin_amdgcn_mfma_f32_16x16x32_bf16(kf1, qfl, z, 0, 0, 0);
            const float* tq = &tabs[tb_l - k0];
            float e0 = fexp2(t0[0]) * tq[0];
            float e1 = fexp2(t0[1]) * tq[-1];
            float e2 = fexp2(t0[2]) * tq[-2];
            float e3 = fexp2(t0[3]) * tq[-3];
            unsigned p0 = pack_bf16(e0, e1);
            unsigned p1 = pack_bf16(e2, e3);
            float f0 = fexp2(t1[0]) * tq[-4];
            float f1 = fexp2(t1[1]) * tq[-5];
            float f2 = fexp2(t1[2]) * tq[-6];
            float f3 = fexp2(t1[3]) * tq[-7];
            unsigned p2 = pack_bf16(f0, f1);
            unsigned p3 = pack_bf16(f2, f3);
            lsl_s += ((e0 + e1) + (e2 + e3)) + ((f0 + f1) + (f2 + f3));
            short8 pf = mk_s8(p0, p1, p2, p3);
            ol0 = __builtin_amdgcn_mfma_f32_16x16x32_bf16(pf, vf0, ol0, 0, 0, 0);
            ol1 = __builtin_amdgcn_mfma_f32_16x16x32_bf16(pf, vf1, ol1, 0, 0, 0);
        }
    }

    // ---- per-lane denominator -> full per-q sums within wave
    lsh_s += __shfl_xor(lsh_s, 16, 64);
    lsh_s += __shfl_xor(lsh_s, 32, 64);
    lsl_s += __shfl_xor(lsl_s, 16, 64);
    lsl_s += __shfl_xor(lsl_s, 32, 64);
    if (lane < 16) {
        LsB[wv * 32 + lane] = lsh_s;
        LsB[wv * 32 + 16 + lane] = lsl_s;
    }

    // ---- cross-wave O combine tree
    float* cp = &ShA[((wv >> 1) * 64 + lane) * 20];
    if (wv & 1) {
        *(float4*)&cp[0]  = (float4){oh0[0], oh0[1], oh0[2], oh0[3]};
        *(float4*)&cp[4]  = (float4){oh1[0], oh1[1], oh1[2], oh1[3]};
        *(float4*)&cp[8]  = (float4){ol0[0], ol0[1], ol0[2], ol0[3]};
        *(float4*)&cp[12] = (float4){ol1[0], ol1[1], ol1[2], ol1[3]};
    }
    __syncthreads();
    if (!(wv & 1)) {
#pragma unroll
        for (int i = 0; i < 4; i++) {
            oh0[i] += cp[i];      oh1[i] += cp[4 + i];
            ol0[i] += cp[8 + i];  ol1[i] += cp[12 + i];
        }
    }
    __syncthreads();
    if (wv == 2) {
        float* c0 = &ShA[lane * 20];
        *(float4*)&c0[0]  = (float4){oh0[0], oh0[1], oh0[2], oh0[3]};
        *(float4*)&c0[4]  = (float4){oh1[0], oh1[1], oh1[2], oh1[3]};
        *(float4*)&c0[8]  = (float4){ol0[0], ol0[1], ol0[2], ol0[3]};
        *(float4*)&c0[12] = (float4){ol1[0], ol1[1], ol1[2], ol1[3]};
    }
    __syncthreads();
    if (wv == 0) {
        const float* c0 = &ShA[lane * 20];
#pragma unroll
        for (int i = 0; i < 4; i++) {
            oh0[i] += c0[i];      oh1[i] += c0[4 + i];
            ol0[i] += c0[8 + i];  ol1[i] += c0[12 + i];
        }
        int qr = quad * 4;
        int qsrh = qhi0 + qr, qsrl = qlo0 + qr;
#pragma unroll
        for (int r = 0; r < 4; r++) {
            float dh = (LsB[qr + r] + LsB[32 + qr + r]) + (LsB[64 + qr + r] + LsB[96 + qr + r]);
            float dl = (LsB[16 + qr + r] + LsB[48 + qr + r]) + (LsB[80 + qr + r] + LsB[112 + qr + r]);
            float rh = 1.0f / dh;
            float rl = 1.0f / dl;
            size_t bh_ = ((size_t)(b * SEQ + qsrh + r)) * DM + h * DHD;
            size_t bl_ = ((size_t)(b * SEQ + qsrl + r)) * DM + h * DHD;
            *(unsigned*)&ob[bh_ + 2 * l16] = pack_bf16(oh0[r] * rh, oh1[r] * rh);
            *(unsigned*)&ob[bl_ + 2 * l16] = pack_bf16(ol0[r] * rl, ol1[r] * rl);
        }
    }
}

// ---------------------------------------------------------------------------
extern "C" void kernel_launch(void* const* d_in, const int* in_sizes, int n_in,
                              void* d_out, int out_size, void* d_ws, size_t ws_size,
                              hipStream_t stream) {
    const int*   interactions = (const int*)d_in[0];
    const int*   patterns     = (const int*)d_in[1];
    const float* ff           = (const float*)d_in[2];
    const float* inter_emb    = (const float*)d_in[3];
    const float* pattern_emb  = (const float*)d_in[4];
    const float* feat_W       = (const float*)d_in[5];
    const float* feat_b       = (const float*)d_in[6];
    const float* in_W         = (const float*)d_in[7];
    const float* in_b         = (const float*)d_in[8];
    const float* time_W       = (const float*)d_in[9];
    const float* time_b       = (const float*)d_in[10];
    const float* pos_W        = (const float*)d_in[11];
    const float* pos_b        = (const float*)d_in[12];
    const float* Wq           = (const float*)d_in[13];
    const float* bq           = (const float*)d_in[14];
    const float* Wk           = (const float*)d_in[15];
    const float* bk           = (const float*)d_in[16];
    const float* Wv           = (const float*)d_in[17];
    const float* bv           = (const float*)d_in[18];
    const float* Wo           = (const float*)d_in[19];
    const float* bo           = (const float*)d_in[20];
    const float* kerple_p     = (const float*)d_in[21];
    const float* kerple_a     = (const float*)d_in[22];
    const float* ln1_g        = (const float*)d_in[23];
    const float* ln1_b        = (const float*)d_in[24];
    const float* ln2_g        = (const float*)d_in[25];
    const float* ln2_b        = (const float*)d_in[26];
    const float* ffn_W1       = (const float*)d_in[27];
    const float* ffn_b1       = (const float*)d_in[28];
    const float* ffn_W2       = (const float*)d_in[29];
    const float* ffn_b2       = (const float*)d_in[30];
    const float* out_W        = (const float*)d_in[31];
    const float* out_b        = (const float*)d_in[32];
    float* out = (float*)d_out;

    // ---- workspace layout (bytes) ----
    char* wsb = (char*)d_ws;
    const size_t MB = 1024 * 1024;
    float*    x    = (float*)(wsb + 0);          //  8 MB fp32 activations (plain)
    ushort_t* tmpb = (ushort_t*)(wsb + 8  * MB); //  4 MB bf16 residual (perm)
    ushort_t* xb   = (ushort_t*)(wsb + 16 * MB); //  4 MB bf16 x copy (perm)
    ushort_t* qbuf = (ushort_t*)(wsb + 20 * MB); //  4 MB Q (B,H,S,DH) d-perm, pre-scaled
    ushort_t* kbuf = (ushort_t*)(wsb + 24 * MB); //  4 MB K (B,H,S,DH) d-perm
    ushort_t* vtbf = (ushort_t*)(wsb + 28 * MB); //  4 MB V^T (B,H,DH,S) plain
    ushort_t* shrd = (ushort_t*)(wsb + 32 * MB); // 16 MB: cbuf / o_bf / h_bf
    ushort_t* cbuf = shrd;
    ushort_t* o_bf = shrd;
    ushort_t* h_bf = shrd;
    char* wp = wsb + 48 * MB;
    ushort_t* inWt  = (ushort_t*)wp;  wp += 256  * 384 * 2;
    ushort_t* qkvWt = (ushort_t*)wp;  wp += 2 * 768 * 256 * 2;
    ushort_t* WoT   = (ushort_t*)wp;  wp += 2 * 256 * 256 * 2;
    ushort_t* W1T   = (ushort_t*)wp;  wp += 2 * 1024 * 256 * 2;
    ushort_t* W2T   = (ushort_t*)wp;  wp += 2 * 256 * 1024 * 2;
    ushort_t* outWt = (ushort_t*)wp;  wp += 2048 * 256 * 2;

    // ---- weight conversion ----
    ConvArgs ca;
    int D2 = 256 * 256;
    int base = 0, ib = 0;
    auto addseg = [&](const float* src, ushort_t* dst, int K, int N, int Npad, int kp) {
        ca.s[ib].src = src; ca.s[ib].dst = dst; ca.s[ib].K = K; ca.s[ib].N = N;
        ca.s[ib].ntx = Npad / 32; ca.s[ib].base = base; ca.s[ib].kperm = kp;
        base += (Npad / 32) * (K / 32); ib++;
    };
    addseg(in_W,            inWt,           384,  256,  256,  0);
    addseg(Wq,              qkvWt,          256,  256,  256,  1);
    addseg(Wk,              qkvWt + 1 * D2, 256,  256,  256,  1);
    addseg(Wv,              qkvWt + 2 * D2, 256,  256,  256,  1);
    addseg(Wq + D2,         qkvWt + 3 * D2, 256,  256,  256,  1);
    addseg(Wk + D2,         qkvWt + 4 * D2, 256,  256,  256,  1);
    addseg(Wv + D2,         qkvWt + 5 * D2, 256,  256,  256,  1);
    addseg(Wo,              WoT,            256,  256,  256,  1);
    addseg(Wo + D2,         WoT + D2,       256,  256,  256,  1);
    addseg(ffn_W1,          W1T,            256,  1024, 1024, 1);
    addseg(ffn_W1 + 4 * D2, W1T + 4 * D2,   256,  1024, 1024, 1);
    addseg(ffn_W2,          W2T,            1024, 256,  256,  1);
    addseg(ffn_W2 + 4 * D2, W2T + 4 * D2,   1024, 256,  256,  1);
    addseg(out_W,           outWt,          256,  2000, 2048, 1);
    convert_kernel<<<base, 256, 0, stream>>>(ca);

    // ---- input projection (+ fused time/pos encodings) ----
    concat_kernel<<<NTOK, 384, 0, stream>>>(interactions, patterns, ff,
                                            inter_emb, pattern_emb, feat_W, feat_b, cbuf);
    gemm_inproj<<<dim3(128, 4), 256, 0, stream>>>(cbuf, inWt, 256, 384,
                                                  x, xb, in_b, ff, time_W, time_b, pos_W, pos_b);

    for (int l = 0; l < 2; l++) {
        gemm_db<<<dim3(64, 12), 256, 0, stream>>>(
            xb, qkvWt + (size_t)l * 768 * 256, NTOK, 768, 256, 2,
            qbuf, kbuf, vtbf, bq + l * 256, bk + l * 256, bv + l * 256);
        // INSTRUMENT: attn split into two half-grid dispatches (~24 us each)
        // so the rocprof top-5 cutoff drops and hidden kernels surface.
        attn_mfma<<<1024, 256, 0, stream>>>(
            qbuf, kbuf, vtbf, kerple_p + l * NHD, kerple_a + l * NHD, o_bf, 0);
        attn_mfma<<<1024, 256, 0, stream>>>(
            qbuf, kbuf, vtbf, kerple_p + l * NHD, kerple_a + l * NHD, o_bf, 1024);
        gemm_wo<<<dim3(128, 4), 256, 0, stream>>>(
            o_bf, WoT + (size_t)l * D2, 256, 256, tmpb, bo + l * 256);
        ln_kernel<<<NTOK / 16, 256, 0, stream>>>(x, tmpb, ln1_g + l * 256, ln1_b + l * 256, xb);
        gemm_db<<<dim3(64, 16), 256, 0, stream>>>(
            xb, W1T + (size_t)l * 4 * D2, NTOK, 1024, 256, 1,
            h_bf, nullptr, nullptr, ffn_b1 + l * 1024, nullptr, nullptr);
        gemm_ffn2<<<dim3(64, 4), 256, 0, stream>>>(
            h_bf, W2T + (size_t)l * 4 * D2, 256, 1024, tmpb, ffn_b2 + l * 256);
        ln_kernel<<<NTOK / 16, 256, 0, stream>>>(x, tmpb, ln2_g + l * 256, ln2_b + l * 256, xb);
    }

    // ---- output projection (N=2048 padded, guard to 2000, plain fp32 out) ----
    gemm_out<<<dim3(64, 16), 256, 0, stream>>>(
        xb, outWt, NTOK, 2048, 256, out, out_b, NSKC);
}

// Round 10
// 410.431 us; speedup vs baseline: 1.0093x; 1.0093x over previous
//
#include <hip/hip_runtime.h>
#include <math.h>

// B=4, S=2048, F=8, D=256, H=8, L=2, FF=1024, NSK=2000
#define SEQ   2048
#define BATCH 4
#define NTOK  8192
#define DM    256
#define NHD   8
#define DHD   32
#define DFF   1024
#define NSKC  2000

typedef __attribute__((ext_vector_type(8))) short short8;
typedef __attribute__((ext_vector_type(4))) float f32x4;
typedef unsigned short ushort_t;

// 1/sqrt(32) * log2(e): folded into Q so scores come out in exp2 domain.
#define QPRE ((float)(0.17677669529663687 * 1.4426950408889634))

// pair-interleave permutation within each 32-element block
#define SPERM(i) (((i) & ~31) | (((i) & 15) << 1) | (((i) >> 4) & 1))

__device__ __forceinline__ ushort_t f2bf(float x) {
    union { float f; unsigned u; } c; c.f = x;
    unsigned r = c.u + 0x7FFFu + ((c.u >> 16) & 1u);
    return (ushort_t)(r >> 16);
}

#if __has_builtin(__builtin_amdgcn_cvt_pk_bf16_f32)
typedef __attribute__((ext_vector_type(2))) __bf16 bf16x2_t;
__device__ __forceinline__ unsigned pack_bf16(float a, float b) {
    bf16x2_t r = __builtin_amdgcn_cvt_pk_bf16_f32(a, b);
    union { bf16x2_t v; unsigned u; } c; c.v = r;
    return c.u;
}
#else
__device__ __forceinline__ unsigned pack_bf16(float a, float b) {
    return (unsigned)f2bf(a) | ((unsigned)f2bf(b) << 16);
}
#endif

#if __has_builtin(__builtin_amdgcn_exp2f)
__device__ __forceinline__ float fexp2(float x) { return __builtin_amdgcn_exp2f(x); }
#else
__device__ __forceinline__ float fexp2(float x) { return exp2f(x); }
#endif

__device__ __forceinline__ float bf2f(ushort_t x) {
    union { unsigned u; float f; } c; c.u = ((unsigned)x) << 16;
    return c.f;
}

__device__ __forceinline__ float bf2f_lo(unsigned w) {
    union { unsigned u; float f; } c; c.u = w << 16;
    return c.f;
}
__device__ __forceinline__ float bf2f_hi(unsigned w) {
    union { unsigned u; float f; } c; c.u = w & 0xFFFF0000u;
    return c.f;
}

__device__ __forceinline__ short8 mk_s8(unsigned a, unsigned b, unsigned c, unsigned d) {
    union { unsigned u[4]; short8 s; } t;
    t.u[0] = a; t.u[1] = b; t.u[2] = c; t.u[3] = d;
    return t.s;
}

// ---------------------------------------------------------------------------
// Weight conversion, exact tile grid: dst[n][kperm(k)] = bf16(src[k][n]).
// ---------------------------------------------------------------------------
struct ConvSeg { const float* src; ushort_t* dst; int K; int N; int ntx; int base; int kperm; };
struct ConvArgs { ConvSeg s[14]; };

__global__ __launch_bounds__(256) void convert_kernel(ConvArgs args) {
    int bid = blockIdx.x;
    int si = 0;
#pragma unroll
    for (int i = 1; i < 14; i++) if (bid >= args.s[i].base) si = i;
    ConvSeg sg = args.s[si];
    int local = bid - sg.base;
    int ty = local / sg.ntx;
    int tx = local - ty * sg.ntx;
    int n0 = tx * 32, k0 = ty * 32;
    __shared__ float T[32][33];
    int tid = threadIdx.x;
    int tn = tid & 31, tk4 = tid >> 5;
#pragma unroll
    for (int i = 0; i < 4; i++) {
        int kl = tk4 + i * 8;
        float v = 0.0f;
        if (n0 + tn < sg.N) v = sg.src[(size_t)(k0 + kl) * sg.N + n0 + tn];
        T[kl][tn] = v;
    }
    __syncthreads();
    int tk = tid & 31, tn4 = tid >> 5;
    int tks = sg.kperm ? (((tk & 15) << 1) | ((tk >> 4) & 1)) : tk;
#pragma unroll
    for (int i = 0; i < 4; i++) {
        int nl = tn4 + i * 8;
        sg.dst[(size_t)(n0 + nl) * sg.K + k0 + tks] = f2bf(T[tk][nl]);
    }
}

// ---------------------------------------------------------------------------
// concat row [inter_e(256) | pat_e(64) | feat_e(64)] -> bf16 (plain layout)
// ---------------------------------------------------------------------------
__global__ __launch_bounds__(384) void concat_kernel(
    const int* __restrict__ interactions, const int* __restrict__ patterns,
    const float* __restrict__ ff, const float* __restrict__ inter_emb,
    const float* __restrict__ pattern_emb, const float* __restrict__ feat_W,
    const float* __restrict__ feat_b, ushort_t* __restrict__ out)
{
    int tok = blockIdx.x;
    int j = threadIdx.x;
    float v;
    if (j < 256) {
        v = inter_emb[(size_t)interactions[tok] * 256 + j];
    } else if (j < 320) {
        v = pattern_emb[patterns[tok] * 64 + (j - 256)];
    } else {
        int c = j - 320;
        float acc = feat_b[c];
#pragma unroll
        for (int f = 0; f < 8; f++) acc += ff[tok * 8 + f] * feat_W[f * 64 + c];
        v = acc;
    }
    out[(size_t)tok * 384 + j] = f2bf(v);
}

// ---------------------------------------------------------------------------
// ln_kernel v2 (vectorized): LayerNorm(x + r) in place. 16 rows/block.
// ---------------------------------------------------------------------------
__global__ __launch_bounds__(256) void ln_kernel(
    float* __restrict__ x, const ushort_t* __restrict__ r,
    const float* __restrict__ g, const float* __restrict__ b,
    ushort_t* __restrict__ xb)
{
    int t = threadIdx.x;
    int row = blockIdx.x * 16 + (t >> 4);
    int k = t & 15;
    int d0 = (k >> 1) * 32 + (k & 1) * 8;   // lower 8 at d0.., upper 8 at d0+16..
    int p0 = (k >> 1) * 32 + (k & 1) * 16;  // permuted byte-pair base
    size_t rowb = (size_t)row * DM;

    float4 xl0 = *(const float4*)&x[rowb + d0];
    float4 xl1 = *(const float4*)&x[rowb + d0 + 4];
    float4 xh0 = *(const float4*)&x[rowb + d0 + 16];
    float4 xh1 = *(const float4*)&x[rowb + d0 + 20];
    uint4 r0 = *(const uint4*)&r[rowb + p0];
    uint4 r1 = *(const uint4*)&r[rowb + p0 + 8];

    float vlo[8], vhi[8];
    unsigned rw[8] = {r0.x, r0.y, r0.z, r0.w, r1.x, r1.y, r1.z, r1.w};
    const float* xlp0 = (const float*)&xl0;
    const float* xlp1 = (const float*)&xl1;
    const float* xhp0 = (const float*)&xh0;
    const float* xhp1 = (const float*)&xh1;
#pragma unroll
    for (int i = 0; i < 4; i++) {
        vlo[i]     = xlp0[i] + bf2f_lo(rw[i]);
        vlo[4 + i] = xlp1[i] + bf2f_lo(rw[4 + i]);
        vhi[i]     = xhp0[i] + bf2f_hi(rw[i]);
        vhi[4 + i] = xhp1[i] + bf2f_hi(rw[4 + i]);
    }

    float s1 = 0.f, s2 = 0.f;
#pragma unroll
    for (int i = 0; i < 8; i++) {
        s1 += vlo[i] + vhi[i];
        s2 += vlo[i] * vlo[i] + vhi[i] * vhi[i];
    }
#pragma unroll
    for (int off = 1; off < 16; off <<= 1) {
        s1 += __shfl_xor(s1, off, 16);
        s2 += __shfl_xor(s2, off, 16);
    }
    float mean = s1 * (1.0f / 256.0f);
    float var = s2 * (1.0f / 256.0f) - mean * mean;
    float inv = rsqrtf(var + 1e-6f);

    float4 gl0 = *(const float4*)&g[d0];
    float4 gl1 = *(const float4*)&g[d0 + 4];
    float4 gh0 = *(const float4*)&g[d0 + 16];
    float4 gh1 = *(const float4*)&g[d0 + 20];
    float4 bl0 = *(const float4*)&b[d0];
    float4 bl1 = *(const float4*)&b[d0 + 4];
    float4 bh0 = *(const float4*)&b[d0 + 16];
    float4 bh1 = *(const float4*)&b[d0 + 20];
    const float* glp0 = (const float*)&gl0; const float* glp1 = (const float*)&gl1;
    const float* ghp0 = (const float*)&gh0; const float* ghp1 = (const float*)&gh1;
    const float* blp0 = (const float*)&bl0; const float* blp1 = (const float*)&bl1;
    const float* bhp0 = (const float*)&bh0; const float* bhp1 = (const float*)&bh1;

    float nlo[8], nhi[8];
#pragma unroll
    for (int i = 0; i < 4; i++) {
        nlo[i]     = glp0[i] * (vlo[i] - mean) * inv + blp0[i];
        nlo[4 + i] = glp1[i] * (vlo[4 + i] - mean) * inv + blp1[i];
        nhi[i]     = ghp0[i] * (vhi[i] - mean) * inv + bhp0[i];
        nhi[4 + i] = ghp1[i] * (vhi[4 + i] - mean) * inv + bhp1[i];
    }

    *(float4*)&x[rowb + d0]      = (float4){nlo[0], nlo[1], nlo[2], nlo[3]};
    *(float4*)&x[rowb + d0 + 4]  = (float4){nlo[4], nlo[5], nlo[6], nlo[7]};
    *(float4*)&x[rowb + d0 + 16] = (float4){nhi[0], nhi[1], nhi[2], nhi[3]};
    *(float4*)&x[rowb + d0 + 20] = (float4){nhi[4], nhi[5], nhi[6], nhi[7]};
    uint4 o0, o1;
    o0.x = pack_bf16(nlo[0], nhi[0]); o0.y = pack_bf16(nlo[1], nhi[1]);
    o0.z = pack_bf16(nlo[2], nhi[2]); o0.w = pack_bf16(nlo[3], nhi[3]);
    o1.x = pack_bf16(nlo[4], nhi[4]); o1.y = pack_bf16(nlo[5], nhi[5]);
    o1.z = pack_bf16(nlo[6], nhi[6]); o1.w = pack_bf16(nlo[7], nhi[7]);
    *(uint4*)&xb[rowb + p0]     = o0;
    *(uint4*)&xb[rowb + p0 + 8] = o1;
}

// ---------------------------------------------------------------------------
// gemm_inproj: gemm64 geometry (BM=64 BN=64 BK=32, 4 waves x 16x64),
// mode-4 epilogue hardcoded.
// ---------------------------------------------------------------------------
__global__ __launch_bounds__(256) void gemm_inproj(
    const ushort_t* __restrict__ A, const ushort_t* __restrict__ Bt,
    int N, int K,
    float* __restrict__ Cf, ushort_t* __restrict__ Cb,
    const float* __restrict__ b0,
    const float* __restrict__ ffg, const float* __restrict__ tW,
    const float* __restrict__ tb, const float* __restrict__ pW,
    const float* __restrict__ pb)
{
    __shared__ ushort_t As[2][64][40];
    __shared__ ushort_t Bs[2][64][40];
    int m0 = blockIdx.x * 64, n0 = blockIdx.y * 64;
    int tid = threadIdx.x;
    int wv = tid >> 6, lane = tid & 63;
    int quad = lane >> 4, l16 = lane & 15;
    int srow = tid >> 2, sc = (tid & 3) << 3;

    f32x4 acc[4];
#pragma unroll
    for (int j = 0; j < 4; j++) acc[j] = (f32x4){0.f, 0.f, 0.f, 0.f};

    uint4 pa = *(const uint4*)&A[(size_t)(m0 + srow) * K + sc];
    uint4 pbv = *(const uint4*)&Bt[(size_t)(n0 + srow) * K + sc];
    *(uint4*)&As[0][srow][sc] = pa;
    *(uint4*)&Bs[0][srow][sc] = pbv;

    int mrow = wv * 16;
    for (int k0 = 0; k0 < K; k0 += 32) {
        int cur = (k0 >> 5) & 1;
        __syncthreads();
        bool more = (k0 + 32 < K);
        if (more) {
            pa = *(const uint4*)&A[(size_t)(m0 + srow) * K + k0 + 32 + sc];
            pbv = *(const uint4*)&Bt[(size_t)(n0 + srow) * K + k0 + 32 + sc];
        }
        short8 af = *(const short8*)&As[cur][mrow + l16][quad * 8];
        short8 bf0 = *(const short8*)&Bs[cur][l16][quad * 8];
        short8 bf1 = *(const short8*)&Bs[cur][16 + l16][quad * 8];
        short8 bf2 = *(const short8*)&Bs[cur][32 + l16][quad * 8];
        short8 bf3 = *(const short8*)&Bs[cur][48 + l16][quad * 8];
        acc[0] = __builtin_amdgcn_mfma_f32_16x16x32_bf16(af, bf0, acc[0], 0, 0, 0);
        acc[1] = __builtin_amdgcn_mfma_f32_16x16x32_bf16(af, bf1, acc[1], 0, 0, 0);
        acc[2] = __builtin_amdgcn_mfma_f32_16x16x32_bf16(af, bf2, acc[2], 0, 0, 0);
        acc[3] = __builtin_amdgcn_mfma_f32_16x16x32_bf16(af, bf3, acc[3], 0, 0, 0);
        if (more) {
            *(uint4*)&As[cur ^ 1][srow][sc] = pa;
            *(uint4*)&Bs[cur ^ 1][srow][sc] = pbv;
        }
    }

#pragma unroll
    for (int r = 0; r < 4; r++) {
        int m = m0 + mrow + quad * 4 + r;
        int s = m & (SEQ - 1);
        float el = ffg[m * 8];
        float pos = (float)s * (1.0f / (float)SEQ);
#pragma unroll
        for (int nt = 0; nt < 4; nt += 2) {
            int nlo = n0 + nt * 16 + l16;
            int nhi = nlo + 16;
            float v0 = acc[nt][r] + b0[nlo] + tanhf(el * tW[nlo] + tb[nlo]) + pos * pW[nlo] + pb[nlo];
            float v1 = acc[nt + 1][r] + b0[nhi] + tanhf(el * tW[nhi] + tb[nhi]) + pos * pW[nhi] + pb[nhi];
            Cf[(size_t)m * N + nlo] = v0;
            Cf[(size_t)m * N + nhi] = v1;
            *(unsigned*)&Cb[(size_t)m * N + n0 + nt * 16 + 2 * l16] = pack_bf16(v0, v1);
        }
    }
}

// ---------------------------------------------------------------------------
// gemm_wo: gemm64 geometry, mode-5 epilogue hardcoded. (in-chain, unchanged)
// ---------------------------------------------------------------------------
__global__ __launch_bounds__(256) void gemm_wo(
    const ushort_t* __restrict__ A, const ushort_t* __restrict__ Bt,
    int N, int K,
    ushort_t* __restrict__ Cb, const float* __restrict__ b0)
{
    __shared__ ushort_t As[2][64][40];
    __shared__ ushort_t Bs[2][64][40];
    int m0 = blockIdx.x * 64, n0 = blockIdx.y * 64;
    int tid = threadIdx.x;
    int wv = tid >> 6, lane = tid & 63;
    int quad = lane >> 4, l16 = lane & 15;
    int srow = tid >> 2, sc = (tid & 3) << 3;

    f32x4 acc[4];
#pragma unroll
    for (int j = 0; j < 4; j++) acc[j] = (f32x4){0.f, 0.f, 0.f, 0.f};

    uint4 pa = *(const uint4*)&A[(size_t)(m0 + srow) * K + sc];
    uint4 pbv = *(const uint4*)&Bt[(size_t)(n0 + srow) * K + sc];
    *(uint4*)&As[0][srow][sc] = pa;
    *(uint4*)&Bs[0][srow][sc] = pbv;

    int mrow = wv * 16;
    for (int k0 = 0; k0 < K; k0 += 32) {
        int cur = (k0 >> 5) & 1;
        __syncthreads();
        bool more = (k0 + 32 < K);
        if (more) {
            pa = *(const uint4*)&A[(size_t)(m0 + srow) * K + k0 + 32 + sc];
            pbv = *(const uint4*)&Bt[(size_t)(n0 + srow) * K + k0 + 32 + sc];
        }
        short8 af = *(const short8*)&As[cur][mrow + l16][quad * 8];
        short8 bf0 = *(const short8*)&Bs[cur][l16][quad * 8];
        short8 bf1 = *(const short8*)&Bs[cur][16 + l16][quad * 8];
        short8 bf2 = *(const short8*)&Bs[cur][32 + l16][quad * 8];
        short8 bf3 = *(const short8*)&Bs[cur][48 + l16][quad * 8];
        acc[0] = __builtin_amdgcn_mfma_f32_16x16x32_bf16(af, bf0, acc[0], 0, 0, 0);
        acc[1] = __builtin_amdgcn_mfma_f32_16x16x32_bf16(af, bf1, acc[1], 0, 0, 0);
        acc[2] = __builtin_amdgcn_mfma_f32_16x16x32_bf16(af, bf2, acc[2], 0, 0, 0);
        acc[3] = __builtin_amdgcn_mfma_f32_16x16x32_bf16(af, bf3, acc[3], 0, 0, 0);
        if (more) {
            *(uint4*)&As[cur ^ 1][srow][sc] = pa;
            *(uint4*)&Bs[cur ^ 1][srow][sc] = pbv;
        }
    }

#pragma unroll
    for (int r = 0; r < 4; r++) {
        int m = m0 + mrow + quad * 4 + r;
#pragma unroll
        for (int nt = 0; nt < 4; nt += 2) {
            int nlo = n0 + nt * 16 + l16;
            float v0 = acc[nt][r] + b0[nlo];
            float v1 = acc[nt + 1][r] + b0[nlo + 16];
            *(unsigned*)&Cb[(size_t)m * N + n0 + nt * 16 + 2 * l16] = pack_bf16(v0, v1);
        }
    }
}

// ---------------------------------------------------------------------------
// gemm_wo_probe: EXACT clone of gemm_wo with the whole K-pass repeated 2x
// (accumulating into the same acc; output written to scratch). Launched at
// STREAM END. Same kernel, same input region, different stream position.
// If the ~40us/slot cost is intrinsic -> probe ~= 80us, tops rocprof with
// full counters. If positional -> probe ~= 10us, invisible.
// ---------------------------------------------------------------------------
__global__ __launch_bounds__(256) void gemm_wo_probe(
    const ushort_t* __restrict__ A, const ushort_t* __restrict__ Bt,
    int N, int K,
    ushort_t* __restrict__ Cb, const float* __restrict__ b0)
{
    __shared__ ushort_t As[2][64][40];
    __shared__ ushort_t Bs[2][64][40];
    int m0 = blockIdx.x * 64, n0 = blockIdx.y * 64;
    int tid = threadIdx.x;
    int wv = tid >> 6, lane = tid & 63;
    int quad = lane >> 4, l16 = lane & 15;
    int srow = tid >> 2, sc = (tid & 3) << 3;
    int mrow = wv * 16;

    f32x4 acc[4];
#pragma unroll
    for (int j = 0; j < 4; j++) acc[j] = (f32x4){0.f, 0.f, 0.f, 0.f};

    for (int rep = 0; rep < 2; rep++) {
        uint4 pa = *(const uint4*)&A[(size_t)(m0 + srow) * K + sc];
        uint4 pbv = *(const uint4*)&Bt[(size_t)(n0 + srow) * K + sc];
        __syncthreads();   // all waves done reading LDS from previous rep
        *(uint4*)&As[0][srow][sc] = pa;
        *(uint4*)&Bs[0][srow][sc] = pbv;

        for (int k0 = 0; k0 < K; k0 += 32) {
            int cur = (k0 >> 5) & 1;
            __syncthreads();
            bool more = (k0 + 32 < K);
            if (more) {
                pa = *(const uint4*)&A[(size_t)(m0 + srow) * K + k0 + 32 + sc];
                pbv = *(const uint4*)&Bt[(size_t)(n0 + srow) * K + k0 + 32 + sc];
            }
            short8 af = *(const short8*)&As[cur][mrow + l16][quad * 8];
            short8 bf0 = *(const short8*)&Bs[cur][l16][quad * 8];
            short8 bf1 = *(const short8*)&Bs[cur][16 + l16][quad * 8];
            short8 bf2 = *(const short8*)&Bs[cur][32 + l16][quad * 8];
            short8 bf3 = *(const short8*)&Bs[cur][48 + l16][quad * 8];
            acc[0] = __builtin_amdgcn_mfma_f32_16x16x32_bf16(af, bf0, acc[0], 0, 0, 0);
            acc[1] = __builtin_amdgcn_mfma_f32_16x16x32_bf16(af, bf1, acc[1], 0, 0, 0);
            acc[2] = __builtin_amdgcn_mfma_f32_16x16x32_bf16(af, bf2, acc[2], 0, 0, 0);
            acc[3] = __builtin_amdgcn_mfma_f32_16x16x32_bf16(af, bf3, acc[3], 0, 0, 0);
            if (more) {
                *(uint4*)&As[cur ^ 1][srow][sc] = pa;
                *(uint4*)&Bs[cur ^ 1][srow][sc] = pbv;
            }
        }
    }

#pragma unroll
    for (int r = 0; r < 4; r++) {
        int m = m0 + mrow + quad * 4 + r;
#pragma unroll
        for (int nt = 0; nt < 4; nt += 2) {
            int nlo = n0 + nt * 16 + l16;
            float v0 = acc[nt][r] + b0[nlo];
            float v1 = acc[nt + 1][r] + b0[nlo + 16];
            *(unsigned*)&Cb[(size_t)m * N + n0 + nt * 16 + 2 * l16] = pack_bf16(v0, v1);
        }
    }
}

// ---------------------------------------------------------------------------
// gemm_ffn2: gemm_db geometry (BM=128 BN=64, 8 mfma/iter/wave) for FFN2
// (M=8192, N=256, K=1024), bias-only packed-bf16 epilogue. Grid (64,4).
// ---------------------------------------------------------------------------
__global__ __launch_bounds__(256) void gemm_ffn2(
    const ushort_t* __restrict__ A, const ushort_t* __restrict__ Bt,
    int N, int K,
    ushort_t* __restrict__ Cb, const float* __restrict__ b0)
{
    __shared__ ushort_t As[2][128][40];
    __shared__ ushort_t Bs[2][64][40];
    int m0 = blockIdx.x * 128, n0 = blockIdx.y * 64;
    int tid = threadIdx.x;
    int wv = tid >> 6, lane = tid & 63;
    int quad = lane >> 4, l16 = lane & 15;
    int srow = tid >> 2, sc = (tid & 3) << 3;

    f32x4 acc[2][4];
#pragma unroll
    for (int i = 0; i < 2; i++)
#pragma unroll
        for (int j = 0; j < 4; j++) acc[i][j] = (f32x4){0.f, 0.f, 0.f, 0.f};

    uint4 pa0 = *(const uint4*)&A[(size_t)(m0 + srow) * K + sc];
    uint4 pa1 = *(const uint4*)&A[(size_t)(m0 + 64 + srow) * K + sc];
    uint4 pbb = *(const uint4*)&Bt[(size_t)(n0 + srow) * K + sc];
    *(uint4*)&As[0][srow][sc] = pa0;
    *(uint4*)&As[0][64 + srow][sc] = pa1;
    *(uint4*)&Bs[0][srow][sc] = pbb;

    int msub = wv * 32;
    for (int k0 = 0; k0 < K; k0 += 32) {
        int cur = (k0 >> 5) & 1;
        __syncthreads();
        bool more = (k0 + 32 < K);
        if (more) {
            pa0 = *(const uint4*)&A[(size_t)(m0 + srow) * K + k0 + 32 + sc];
            pa1 = *(const uint4*)&A[(size_t)(m0 + 64 + srow) * K + k0 + 32 + sc];
            pbb = *(const uint4*)&Bt[(size_t)(n0 + srow) * K + k0 + 32 + sc];
        }
        short8 af0 = *(const short8*)&As[cur][msub + l16][quad * 8];
        short8 af1 = *(const short8*)&As[cur][msub + 16 + l16][quad * 8];
        short8 bf0 = *(const short8*)&Bs[cur][l16][quad * 8];
        short8 bf1 = *(const short8*)&Bs[cur][16 + l16][quad * 8];
        short8 bf2 = *(const short8*)&Bs[cur][32 + l16][quad * 8];
        short8 bf3 = *(const short8*)&Bs[cur][48 + l16][quad * 8];
        acc[0][0] = __builtin_amdgcn_mfma_f32_16x16x32_bf16(af0, bf0, acc[0][0], 0, 0, 0);
        acc[0][1] = __builtin_amdgcn_mfma_f32_16x16x32_bf16(af0, bf1, acc[0][1], 0, 0, 0);
        acc[0][2] = __builtin_amdgcn_mfma_f32_16x16x32_bf16(af0, bf2, acc[0][2], 0, 0, 0);
        acc[0][3] = __builtin_amdgcn_mfma_f32_16x16x32_bf16(af0, bf3, acc[0][3], 0, 0, 0);
        acc[1][0] = __builtin_amdgcn_mfma_f32_16x16x32_bf16(af1, bf0, acc[1][0], 0, 0, 0);
        acc[1][1] = __builtin_amdgcn_mfma_f32_16x16x32_bf16(af1, bf1, acc[1][1], 0, 0, 0);
        acc[1][2] = __builtin_amdgcn_mfma_f32_16x16x32_bf16(af1, bf2, acc[1][2], 0, 0, 0);
        acc[1][3] = __builtin_amdgcn_mfma_f32_16x16x32_bf16(af1, bf3, acc[1][3], 0, 0, 0);
        if (more) {
            *(uint4*)&As[cur ^ 1][srow][sc] = pa0;
            *(uint4*)&As[cur ^ 1][64 + srow][sc] = pa1;
            *(uint4*)&Bs[cur ^ 1][srow][sc] = pbb;
        }
    }

#pragma unroll
    for (int mt = 0; mt < 2; mt++) {
#pragma unroll
        for (int nt = 0; nt < 4; nt += 2) {
            int nlo = n0 + nt * 16 + l16;
#pragma unroll
            for (int r = 0; r < 4; r++) {
                int m = m0 + msub + mt * 16 + quad * 4 + r;
                float t0 = acc[mt][nt][r] + b0[nlo];
                float t1 = acc[mt][nt + 1][r] + b0[nlo + 16];
                *(unsigned*)&Cb[(size_t)m * N + n0 + nt * 16 + 2 * l16] = pack_bf16(t0, t1);
            }
        }
    }
}

// ---------------------------------------------------------------------------
// gemm_db: BM=128 BN=64 BK=32, double-buffered (1 barrier/iter).
// mode 1: gelu -> packed bf16
// mode 2: QKV epilogue
// ---------------------------------------------------------------------------
__global__ __launch_bounds__(256) void gemm_db(
    const ushort_t* __restrict__ A, const ushort_t* __restrict__ Bt,
    int M, int N, int K, int mode,
    ushort_t* __restrict__ Cb, ushort_t* __restrict__ Ck, ushort_t* __restrict__ Cv,
    const float* __restrict__ b0, const float* __restrict__ b1,
    const float* __restrict__ b2)
{
    __shared__ ushort_t As[2][128][40];
    __shared__ ushort_t Bs[2][64][40];
    int m0 = blockIdx.x * 128, n0 = blockIdx.y * 64;
    int tid = threadIdx.x;
    int wv = tid >> 6, lane = tid & 63;
    int quad = lane >> 4, l16 = lane & 15;
    int srow = tid >> 2, sc = (tid & 3) << 3;

    f32x4 acc[2][4];
#pragma unroll
    for (int i = 0; i < 2; i++)
#pragma unroll
        for (int j = 0; j < 4; j++) acc[i][j] = (f32x4){0.f, 0.f, 0.f, 0.f};

    uint4 pa0 = *(const uint4*)&A[(size_t)(m0 + srow) * K + sc];
    uint4 pa1 = *(const uint4*)&A[(size_t)(m0 + 64 + srow) * K + sc];
    uint4 pbb = *(const uint4*)&Bt[(size_t)(n0 + srow) * K + sc];
    *(uint4*)&As[0][srow][sc] = pa0;
    *(uint4*)&As[0][64 + srow][sc] = pa1;
    *(uint4*)&Bs[0][srow][sc] = pbb;

    int msub = wv * 32;
    for (int k0 = 0; k0 < K; k0 += 32) {
        int cur = (k0 >> 5) & 1;
        __syncthreads();
        bool more = (k0 + 32 < K);
        if (more) {
            pa0 = *(const uint4*)&A[(size_t)(m0 + srow) * K + k0 + 32 + sc];
            pa1 = *(const uint4*)&A[(size_t)(m0 + 64 + srow) * K + k0 + 32 + sc];
            pbb = *(const uint4*)&Bt[(size_t)(n0 + srow) * K + k0 + 32 + sc];
        }
        short8 af0 = *(const short8*)&As[cur][msub + l16][quad * 8];
        short8 af1 = *(const short8*)&As[cur][msub + 16 + l16][quad * 8];
        short8 bf0 = *(const short8*)&Bs[cur][l16][quad * 8];
        short8 bf1 = *(const short8*)&Bs[cur][16 + l16][quad * 8];
        short8 bf2 = *(const short8*)&Bs[cur][32 + l16][quad * 8];
        short8 bf3 = *(const short8*)&Bs[cur][48 + l16][quad * 8];
        acc[0][0] = __builtin_amdgcn_mfma_f32_16x16x32_bf16(af0, bf0, acc[0][0], 0, 0, 0);
        acc[0][1] = __builtin_amdgcn_mfma_f32_16x16x32_bf16(af0, bf1, acc[0][1], 0, 0, 0);
        acc[0][2] = __builtin_amdgcn_mfma_f32_16x16x32_bf16(af0, bf2, acc[0][2], 0, 0, 0);
        acc[0][3] = __builtin_amdgcn_mfma_f32_16x16x32_bf16(af0, bf3, acc[0][3], 0, 0, 0);
        acc[1][0] = __builtin_amdgcn_mfma_f32_16x16x32_bf16(af1, bf0, acc[1][0], 0, 0, 0);
        acc[1][1] = __builtin_amdgcn_mfma_f32_16x16x32_bf16(af1, bf1, acc[1][1], 0, 0, 0);
        acc[1][2] = __builtin_amdgcn_mfma_f32_16x16x32_bf16(af1, bf2, acc[1][2], 0, 0, 0);
        acc[1][3] = __builtin_amdgcn_mfma_f32_16x16x32_bf16(af1, bf3, acc[1][3], 0, 0, 0);
        if (more) {
            *(uint4*)&As[cur ^ 1][srow][sc] = pa0;
            *(uint4*)&As[cur ^ 1][64 + srow][sc] = pa1;
            *(uint4*)&Bs[cur ^ 1][srow][sc] = pbb;
        }
    }

#pragma unroll
    for (int mt = 0; mt < 2; mt++) {
#pragma unroll
        for (int nt = 0; nt < 4; nt += 2) {
            int nlo = n0 + nt * 16 + l16;
#pragma unroll
            for (int r = 0; r < 4; r++) {
                int m = m0 + msub + mt * 16 + quad * 4 + r;
                float vlo = acc[mt][nt][r];
                float vhi = acc[mt][nt + 1][r];
                if (mode == 1) {
                    float t0 = vlo + b0[nlo];
                    float t1 = vhi + b0[nlo + 16];
                    t0 = 0.5f * t0 * (1.0f + erff(t0 * 0.70710678118654752f));
                    t1 = 0.5f * t1 * (1.0f + erff(t1 * 0.70710678118654752f));
                    *(unsigned*)&Cb[(size_t)m * N + n0 + nt * 16 + 2 * l16] = pack_bf16(t0, t1);
                } else {
                    int which = nlo >> 8, idx = nlo & 255;
                    int hh = idx >> 5;          // d == l16, partner d+16 same head
                    int s = m & (SEQ - 1), b = m >> 11;
                    if (which == 0) {
                        float q0 = (vlo + b0[idx]) * QPRE;
                        float q1 = (vhi + b0[idx + 16]) * QPRE;
                        *(unsigned*)&Cb[(((size_t)(b * NHD + hh)) * SEQ + s) * DHD + 2 * l16] = pack_bf16(q0, q1);
                    } else if (which == 1) {
                        float k0v = vlo + b1[idx];
                        float k1v = vhi + b1[idx + 16];
                        *(unsigned*)&Ck[(((size_t)(b * NHD + hh)) * SEQ + s) * DHD + 2 * l16] = pack_bf16(k0v, k1v);
                    } else {
                        Cv[(((size_t)(b * NHD + hh)) * DHD + l16) * SEQ + s] = f2bf(vlo + b2[idx]);
                        Cv[(((size_t)(b * NHD + hh)) * DHD + l16 + 16) * SEQ + s] = f2bf(vhi + b2[idx + 16]);
                    }
                }
            }
        }
    }
}

// ---------------------------------------------------------------------------
// gemm_out: BM=128 BN=128 BK=32, double-buffered. fp32 + bias, n < Nreal.
// ---------------------------------------------------------------------------
__global__ __launch_bounds__(256) void gemm_out(
    const ushort_t* __restrict__ A, const ushort_t* __restrict__ Bt,
    int M, int N, int K,
    float* __restrict__ Cf, const float* __restrict__ b0, int Nreal)
{
    __shared__ ushort_t As[2][128][40];
    __shared__ ushort_t Bs[2][128][40];
    int m0 = blockIdx.x * 128, n0 = blockIdx.y * 128;
    int tid = threadIdx.x;
    int wv = tid >> 6, lane = tid & 63;
    int quad = lane >> 4, l16 = lane & 15;
    int wm = (wv >> 1) * 64, wn = (wv & 1) * 64;
    int srow = tid >> 1, sc = (tid & 1) << 4;

    f32x4 acc[4][4];
#pragma unroll
    for (int i = 0; i < 4; i++)
#pragma unroll
        for (int j = 0; j < 4; j++) acc[i][j] = (f32x4){0.f, 0.f, 0.f, 0.f};

    uint4 pa0 = *(const uint4*)&A[(size_t)(m0 + srow) * K + sc];
    uint4 pa1 = *(const uint4*)&A[(size_t)(m0 + srow) * K + sc + 8];
    uint4 pb0 = *(const uint4*)&Bt[(size_t)(n0 + srow) * K + sc];
    uint4 pb1 = *(const uint4*)&Bt[(size_t)(n0 + srow) * K + sc + 8];
    *(uint4*)&As[0][srow][sc] = pa0;
    *(uint4*)&As[0][srow][sc + 8] = pa1;
    *(uint4*)&Bs[0][srow][sc] = pb0;
    *(uint4*)&Bs[0][srow][sc + 8] = pb1;

    for (int k0 = 0; k0 < K; k0 += 32) {
        int cur = (k0 >> 5) & 1;
        __syncthreads();
        bool more = (k0 + 32 < K);
        if (more) {
            pa0 = *(const uint4*)&A[(size_t)(m0 + srow) * K + k0 + 32 + sc];
            pa1 = *(const uint4*)&A[(size_t)(m0 + srow) * K + k0 + 32 + sc + 8];
            pb0 = *(const uint4*)&Bt[(size_t)(n0 + srow) * K + k0 + 32 + sc];
            pb1 = *(const uint4*)&Bt[(size_t)(n0 + srow) * K + k0 + 32 + sc + 8];
        }
        short8 af[4], bf[4];
#pragma unroll
        for (int i = 0; i < 4; i++) {
            af[i] = *(const short8*)&As[cur][wm + i * 16 + l16][quad * 8];
            bf[i] = *(const short8*)&Bs[cur][wn + i * 16 + l16][quad * 8];
        }
#pragma unroll
        for (int i = 0; i < 4; i++)
#pragma unroll
            for (int j = 0; j < 4; j++)
                acc[i][j] = __builtin_amdgcn_mfma_f32_16x16x32_bf16(af[i], bf[j], acc[i][j], 0, 0, 0);
        if (more) {
            *(uint4*)&As[cur ^ 1][srow][sc] = pa0;
            *(uint4*)&As[cur ^ 1][srow][sc + 8] = pa1;
            *(uint4*)&Bs[cur ^ 1][srow][sc] = pb0;
            *(uint4*)&Bs[cur ^ 1][srow][sc + 8] = pb1;
        }
    }

#pragma unroll
    for (int i = 0; i < 4; i++) {
#pragma unroll
        for (int j = 0; j < 4; j++) {
            int n = n0 + wn + j * 16 + l16;
            if (n < Nreal) {
#pragma unroll
                for (int r = 0; r < 4; r++) {
                    int m = m0 + wm + i * 16 + quad * 4 + r;
                    Cf[(size_t)m * Nreal + n] = acc[i][j][r] + b0[n];
                }
            }
        }
    }
}

// ---------------------------------------------------------------------------
// MFMA flash attention v4 (swapped-operand, zero P-LDS) -- single dispatch.
// ---------------------------------------------------------------------------
__global__ __launch_bounds__(256) void attn_mfma(
    const ushort_t* __restrict__ qb, const ushort_t* __restrict__ kb,
    const ushort_t* __restrict__ vtb, const float* __restrict__ kp,
    const float* __restrict__ ka, ushort_t* __restrict__ ob)
{
    // gid = (hb>>3)*512 + pj*8 + (hb&7)  (bijective over 2048)
    int gid = blockIdx.x;
    int hb = ((gid >> 9) << 3) | (gid & 7);
    int pj = (gid >> 3) & 63;
    int b = hb >> 3, h = hb & 7;

    int tid = threadIdx.x, wv = tid >> 6, lane = tid & 63;
    int quad = lane >> 4, l16 = lane & 15;

    __shared__ float tabs[2112];
    __shared__ __align__(16) float ShA[2560];   // O-combine, stride 20
    __shared__ float LsB[128];                  // per-wave denominators

    float p = log1pf(__expf(kp[h]));
    float a = log1pf(__expf(ka[h]));
    for (int i = tid; i < 2112; i += 256) {
        float w = 0.0f;
        if (i >= 64) w = fexp2(-p * __log2f(fmaf(a, (float)(i - 64), 1.0f)));
        tabs[i] = w;
    }
    __syncthreads();

    int bh = b * NHD + h;
    const ushort_t* Qh = qb + (size_t)bh * SEQ * DHD;
    const ushort_t* Kh = kb + (size_t)bh * SEQ * DHD;
    const ushort_t* Vh = vtb + (size_t)bh * DHD * SEQ;

    int tlo = pj, thi = 127 - pj;
    int qlo0 = tlo * 16, qhi0 = thi * 16;

    short8 qfl = *(const short8*)&Qh[(qlo0 + l16) * DHD + quad * 8];
    short8 qfh = *(const short8*)&Qh[(qhi0 + l16) * DHD + quad * 8];
    f32x4 ol0 = (f32x4){0.f,0.f,0.f,0.f}, ol1 = (f32x4){0.f,0.f,0.f,0.f};
    f32x4 oh0 = (f32x4){0.f,0.f,0.f,0.f}, oh1 = (f32x4){0.f,0.f,0.f,0.f};
    float lsh_s = 0.f, lsl_s = 0.f;

    int nch_hi = (thi + 2) >> 1;     // >= 33, so every wave gets hi work
    int nch_lo = (tlo + 2) >> 1;     // >= 1
    // permuted K row offset: l16 -> {0-3,8-11,16-19,24-27}
    int krow = ((l16 >> 2) << 3) | (l16 & 3);
    int tb_h = qhi0 + l16 + 64 - 8 * quad;
    int tb_l = qlo0 + l16 + 64 - 8 * quad;

    int ch = wv;
    short8 kf0n, kf1n;
    {
        int k0 = ch * 32;
        kf0n = *(const short8*)&Kh[(k0 + krow) * DHD + quad * 8];
        kf1n = *(const short8*)&Kh[(k0 + 4 + krow) * DHD + quad * 8];
    }

    for (; ch < nch_hi; ch += 4) {
        int k0 = ch * 32;
        short8 kf0 = kf0n, kf1 = kf1n;
        short8 vf0 = *(const short8*)&Vh[l16 * SEQ + k0 + quad * 8];
        short8 vf1 = *(const short8*)&Vh[(16 + l16) * SEQ + k0 + quad * 8];
        int chn = ch + 4;
        if (chn < nch_hi) {
            int kn = chn * 32;
            kf0n = *(const short8*)&Kh[(kn + krow) * DHD + quad * 8];
            kf1n = *(const short8*)&Kh[(kn + 4 + krow) * DHD + quad * 8];
        }
        f32x4 z = (f32x4){0.f,0.f,0.f,0.f};

        // scores: s0[r] = S[k0+8q+r][q=l16], s1[r] = S[k0+8q+4+r][q=l16]
        f32x4 s0 = __builtin_amdgcn_mfma_f32_16x16x32_bf16(kf0, qfh, z, 0, 0, 0);
        f32x4 s1 = __builtin_amdgcn_mfma_f32_16x16x32_bf16(kf1, qfh, z, 0, 0, 0);
        {
            const float* tp = &tabs[tb_h - k0];
            float e0 = fexp2(s0[0]) * tp[0];
            float e1 = fexp2(s0[1]) * tp[-1];
            float e2 = fexp2(s0[2]) * tp[-2];
            float e3 = fexp2(s0[3]) * tp[-3];
            unsigned p0 = pack_bf16(e0, e1);
            unsigned p1 = pack_bf16(e2, e3);
            float f0 = fexp2(s1[0]) * tp[-4];
            float f1 = fexp2(s1[1]) * tp[-5];
            float f2 = fexp2(s1[2]) * tp[-6];
            float f3 = fexp2(s1[3]) * tp[-7];
            unsigned p2 = pack_bf16(f0, f1);
            unsigned p3 = pack_bf16(f2, f3);
            lsh_s += ((e0 + e1) + (e2 + e3)) + ((f0 + f1) + (f2 + f3));
            short8 pf = mk_s8(p0, p1, p2, p3);
            oh0 = __builtin_amdgcn_mfma_f32_16x16x32_bf16(pf, vf0, oh0, 0, 0, 0);
            oh1 = __builtin_amdgcn_mfma_f32_16x16x32_bf16(pf, vf1, oh1, 0, 0, 0);
        }
        if (ch < nch_lo) {
            f32x4 t0 = __builtin_amdgcn_mfma_f32_16x16x32_bf16(kf0, qfl, z, 0, 0, 0);
            f32x4 t1 = __builtin_amdgcn_mfma_f32_16x16x32_bf16(kf1, qfl, z, 0, 0, 0);
            const float* tq = &tabs[tb_l - k0];
            float e0 = fexp2(t0[0]) * tq[0];
            float e1 = fexp2(t0[1]) * tq[-1];
            float e2 = fexp2(t0[2]) * tq[-2];
            float e3 = fexp2(t0[3]) * tq[-3];
            unsigned p0 = pack_bf16(e0, e1);
            unsigned p1 = pack_bf16(e2, e3);
            float f0 = fexp2(t1[0]) * tq[-4];
            float f1 = fexp2(t1[1]) * tq[-5];
            float f2 = fexp2(t1[2]) * tq[-6];
            float f3 = fexp2(t1[3]) * tq[-7];
            unsigned p2 = pack_bf16(f0, f1);
            unsigned p3 = pack_bf16(f2, f3);
            lsl_s += ((e0 + e1) + (e2 + e3)) + ((f0 + f1) + (f2 + f3));
            short8 pf = mk_s8(p0, p1, p2, p3);
            ol0 = __builtin_amdgcn_mfma_f32_16x16x32_bf16(pf, vf0, ol0, 0, 0, 0);
            ol1 = __builtin_amdgcn_mfma_f32_16x16x32_bf16(pf, vf1, ol1, 0, 0, 0);
        }
    }

    // ---- per-lane denominator -> full per-q sums within wave
    lsh_s += __shfl_xor(lsh_s, 16, 64);
    lsh_s += __shfl_xor(lsh_s, 32, 64);
    lsl_s += __shfl_xor(lsl_s, 16, 64);
    lsl_s += __shfl_xor(lsl_s, 32, 64);
    if (lane < 16) {
        LsB[wv * 32 + lane] = lsh_s;
        LsB[wv * 32 + 16 + lane] = lsl_s;
    }

    // ---- cross-wave O combine tree
    float* cp = &ShA[((wv >> 1) * 64 + lane) * 20];
    if (wv & 1) {
        *(float4*)&cp[0]  = (float4){oh0[0], oh0[1], oh0[2], oh0[3]};
        *(float4*)&cp[4]  = (float4){oh1[0], oh1[1], oh1[2], oh1[3]};
        *(float4*)&cp[8]  = (float4){ol0[0], ol0[1], ol0[2], ol0[3]};
        *(float4*)&cp[12] = (float4){ol1[0], ol1[1], ol1[2], ol1[3]};
    }
    __syncthreads();
    if (!(wv & 1)) {
#pragma unroll
        for (int i = 0; i < 4; i++) {
            oh0[i] += cp[i];      oh1[i] += cp[4 + i];
            ol0[i] += cp[8 + i];  ol1[i] += cp[12 + i];
        }
    }
    __syncthreads();
    if (wv == 2) {
        float* c0 = &ShA[lane * 20];
        *(float4*)&c0[0]  = (float4){oh0[0], oh0[1], oh0[2], oh0[3]};
        *(float4*)&c0[4]  = (float4){oh1[0], oh1[1], oh1[2], oh1[3]};
        *(float4*)&c0[8]  = (float4){ol0[0], ol0[1], ol0[2], ol0[3]};
        *(float4*)&c0[12] = (float4){ol1[0], ol1[1], ol1[2], ol1[3]};
    }
    __syncthreads();
    if (wv == 0) {
        const float* c0 = &ShA[lane * 20];
#pragma unroll
        for (int i = 0; i < 4; i++) {
            oh0[i] += c0[i];      oh1[i] += c0[4 + i];
            ol0[i] += c0[8 + i];  ol1[i] += c0[12 + i];
        }
        int qr = quad * 4;
        int qsrh = qhi0 + qr, qsrl = qlo0 + qr;
#pragma unroll
        for (int r = 0; r < 4; r++) {
            float dh = (LsB[qr + r] + LsB[32 + qr + r]) + (LsB[64 + qr + r] + LsB[96 + qr + r]);
            float dl = (LsB[16 + qr + r] + LsB[48 + qr + r]) + (LsB[80 + qr + r] + LsB[112 + qr + r]);
            float rh = 1.0f / dh;
            float rl = 1.0f / dl;
            size_t bh_ = ((size_t)(b * SEQ + qsrh + r)) * DM + h * DHD;
            size_t bl_ = ((size_t)(b * SEQ + qsrl + r)) * DM + h * DHD;
            *(unsigned*)&ob[bh_ + 2 * l16] = pack_bf16(oh0[r] * rh, oh1[r] * rh);
            *(unsigned*)&ob[bl_ + 2 * l16] = pack_bf16(ol0[r] * rl, ol1[r] * rl);
        }
    }
}

// ---------------------------------------------------------------------------
extern "C" void kernel_launch(void* const* d_in, const int* in_sizes, int n_in,
                              void* d_out, int out_size, void* d_ws, size_t ws_size,
                              hipStream_t stream) {
    const int*   interactions = (const int*)d_in[0];
    const int*   patterns     = (const int*)d_in[1];
    const float* ff           = (const float*)d_in[2];
    const float* inter_emb    = (const float*)d_in[3];
    const float* pattern_emb  = (const float*)d_in[4];
    const float* feat_W       = (const float*)d_in[5];
    const float* feat_b       = (const float*)d_in[6];
    const float* in_W         = (const float*)d_in[7];
    const float* in_b         = (const float*)d_in[8];
    const float* time_W       = (const float*)d_in[9];
    const float* time_b       = (const float*)d_in[10];
    const float* pos_W        = (const float*)d_in[11];
    const float* pos_b        = (const float*)d_in[12];
    const float* Wq           = (const float*)d_in[13];
    const float* bq           = (const float*)d_in[14];
    const float* Wk           = (const float*)d_in[15];
    const float* bk           = (const float*)d_in[16];
    const float* Wv           = (const float*)d_in[17];
    const float* bv           = (const float*)d_in[18];
    const float* Wo           = (const float*)d_in[19];
    const float* bo           = (const float*)d_in[20];
    const float* kerple_p     = (const float*)d_in[21];
    const float* kerple_a     = (const float*)d_in[22];
    const float* ln1_g        = (const float*)d_in[23];
    const float* ln1_b        = (const float*)d_in[24];
    const float* ln2_g        = (const float*)d_in[25];
    const float* ln2_b        = (const float*)d_in[26];
    const float* ffn_W1       = (const float*)d_in[27];
    const float* ffn_b1       = (const float*)d_in[28];
    const float* ffn_W2       = (const float*)d_in[29];
    const float* ffn_b2       = (const float*)d_in[30];
    const float* out_W        = (const float*)d_in[31];
    const float* out_b        = (const float*)d_in[32];
    float* out = (float*)d_out;

    // ---- workspace layout (bytes) ----
    char* wsb = (char*)d_ws;
    const size_t MB = 1024 * 1024;
    float*    x    = (float*)(wsb + 0);          //  8 MB fp32 activations (plain)
    ushort_t* tmpb = (ushort_t*)(wsb + 8  * MB); //  4 MB bf16 residual (perm)
    ushort_t* prbb = (ushort_t*)(wsb + 12 * MB); //  4 MB probe scratch (never read)
    ushort_t* xb   = (ushort_t*)(wsb + 16 * MB); //  4 MB bf16 x copy (perm)
    ushort_t* qbuf = (ushort_t*)(wsb + 20 * MB); //  4 MB Q (B,H,S,DH) d-perm, pre-scaled
    ushort_t* kbuf = (ushort_t*)(wsb + 24 * MB); //  4 MB K (B,H,S,DH) d-perm
    ushort_t* vtbf = (ushort_t*)(wsb + 28 * MB); //  4 MB V^T (B,H,DH,S) plain
    ushort_t* shrd = (ushort_t*)(wsb + 32 * MB); // 16 MB: cbuf / o_bf / h_bf
    ushort_t* cbuf = shrd;
    ushort_t* o_bf = shrd;
    ushort_t* h_bf = shrd;
    char* wp = wsb + 48 * MB;
    ushort_t* inWt  = (ushort_t*)wp;  wp += 256  * 384 * 2;
    ushort_t* qkvWt = (ushort_t*)wp;  wp += 2 * 768 * 256 * 2;
    ushort_t* WoT   = (ushort_t*)wp;  wp += 2 * 256 * 256 * 2;
    ushort_t* W1T   = (ushort_t*)wp;  wp += 2 * 1024 * 256 * 2;
    ushort_t* W2T   = (ushort_t*)wp;  wp += 2 * 256 * 1024 * 2;
    ushort_t* outWt = (ushort_t*)wp;  wp += 2048 * 256 * 2;

    // ---- weight conversion ----
    ConvArgs ca;
    int D2 = 256 * 256;
    int base = 0, ib = 0;
    auto addseg = [&](const float* src, ushort_t* dst, int K, int N, int Npad, int kp) {
        ca.s[ib].src = src; ca.s[ib].dst = dst; ca.s[ib].K = K; ca.s[ib].N = N;
        ca.s[ib].ntx = Npad / 32; ca.s[ib].base = base; ca.s[ib].kperm = kp;
        base += (Npad / 32) * (K / 32); ib++;
    };
    addseg(in_W,            inWt,           384,  256,  256,  0);
    addseg(Wq,              qkvWt,          256,  256,  256,  1);
    addseg(Wk,              qkvWt + 1 * D2, 256,  256,  256,  1);
    addseg(Wv,              qkvWt + 2 * D2, 256,  256,  256,  1);
    addseg(Wq + D2,         qkvWt + 3 * D2, 256,  256,  256,  1);
    addseg(Wk + D2,         qkvWt + 4 * D2, 256,  256,  256,  1);
    addseg(Wv + D2,         qkvWt + 5 * D2, 256,  256,  256,  1);
    addseg(Wo,              WoT,            256,  256,  256,  1);
    addseg(Wo + D2,         WoT + D2,       256,  256,  256,  1);
    addseg(ffn_W1,          W1T,            256,  1024, 1024, 1);
    addseg(ffn_W1 + 4 * D2, W1T + 4 * D2,   256,  1024, 1024, 1);
    addseg(ffn_W2,          W2T,            1024, 256,  256,  1);
    addseg(ffn_W2 + 4 * D2, W2T + 4 * D2,   1024, 256,  256,  1);
    addseg(out_W,           outWt,          256,  2000, 2048, 1);
    convert_kernel<<<base, 256, 0, stream>>>(ca);

    // ---- input projection (+ fused time/pos encodings) ----
    concat_kernel<<<NTOK, 384, 0, stream>>>(interactions, patterns, ff,
                                            inter_emb, pattern_emb, feat_W, feat_b, cbuf);
    gemm_inproj<<<dim3(128, 4), 256, 0, stream>>>(cbuf, inWt, 256, 384,
                                                  x, xb, in_b, ff, time_W, time_b, pos_W, pos_b);

    for (int l = 0; l < 2; l++) {
        gemm_db<<<dim3(64, 12), 256, 0, stream>>>(
            xb, qkvWt + (size_t)l * 768 * 256, NTOK, 768, 256, 2,
            qbuf, kbuf, vtbf, bq + l * 256, bk + l * 256, bv + l * 256);
        attn_mfma<<<2048, 256, 0, stream>>>(
            qbuf, kbuf, vtbf, kerple_p + l * NHD, kerple_a + l * NHD, o_bf);
        gemm_wo<<<dim3(128, 4), 256, 0, stream>>>(
            o_bf, WoT + (size_t)l * D2, 256, 256, tmpb, bo + l * 256);
        ln_kernel<<<NTOK / 16, 256, 0, stream>>>(x, tmpb, ln1_g + l * 256, ln1_b + l * 256, xb);
        gemm_db<<<dim3(64, 16), 256, 0, stream>>>(
            xb, W1T + (size_t)l * 4 * D2, NTOK, 1024, 256, 1,
            h_bf, nullptr, nullptr, ffn_b1 + l * 1024, nullptr, nullptr);
        gemm_ffn2<<<dim3(64, 4), 256, 0, stream>>>(
            h_bf, W2T + (size_t)l * 4 * D2, 256, 1024, tmpb, ffn_b2 + l * 256);
        ln_kernel<<<NTOK / 16, 256, 0, stream>>>(x, tmpb, ln2_g + l * 256, ln2_b + l * 256, xb);
    }

    // ---- output projection (N=2048 padded, guard to 2000, plain fp32 out) ----
    gemm_out<<<dim3(64, 16), 256, 0, stream>>>(
        xb, outWt, NTOK, 2048, 256, out, out_b, NSKC);

    // ---- PROBE: gemm_wo clone, same shrd-region input, END of stream,
    //      2x K-pass repeat, writes scratch. Position is the only variable.
    gemm_wo_probe<<<dim3(128, 4), 256, 0, stream>>>(
        o_bf, WoT, 256, 256, prbb, bo);
}

// Round 11
// 397.287 us; speedup vs baseline: 1.0427x; 1.0331x over previous
//
#include <hip/hip_runtime.h>
#include <math.h>

// B=4, S=2048, F=8, D=256, H=8, L=2, FF=1024, NSK=2000
#define SEQ   2048
#define BATCH 4
#define NTOK  8192
#define DM    256
#define NHD   8
#define DHD   32
#define DFF   1024
#define NSKC  2000

typedef __attribute__((ext_vector_type(8))) short short8;
typedef __attribute__((ext_vector_type(4))) float f32x4;
typedef unsigned short ushort_t;

// 1/sqrt(32) * log2(e): folded into Q so scores come out in exp2 domain.
#define QPRE ((float)(0.17677669529663687 * 1.4426950408889634))

// pair-interleave permutation within each 32-element block
#define SPERM(i) (((i) & ~31) | (((i) & 15) << 1) | (((i) >> 4) & 1))

__device__ __forceinline__ ushort_t f2bf(float x) {
    union { float f; unsigned u; } c; c.f = x;
    unsigned r = c.u + 0x7FFFu + ((c.u >> 16) & 1u);
    return (ushort_t)(r >> 16);
}

#if __has_builtin(__builtin_amdgcn_cvt_pk_bf16_f32)
typedef __attribute__((ext_vector_type(2))) __bf16 bf16x2_t;
__device__ __forceinline__ unsigned pack_bf16(float a, float b) {
    bf16x2_t r = __builtin_amdgcn_cvt_pk_bf16_f32(a, b);
    union { bf16x2_t v; unsigned u; } c; c.v = r;
    return c.u;
}
#else
__device__ __forceinline__ unsigned pack_bf16(float a, float b) {
    return (unsigned)f2bf(a) | ((unsigned)f2bf(b) << 16);
}
#endif

#if __has_builtin(__builtin_amdgcn_exp2f)
__device__ __forceinline__ float fexp2(float x) { return __builtin_amdgcn_exp2f(x); }
#else
__device__ __forceinline__ float fexp2(float x) { return exp2f(x); }
#endif

__device__ __forceinline__ float bf2f(ushort_t x) {
    union { unsigned u; float f; } c; c.u = ((unsigned)x) << 16;
    return c.f;
}

__device__ __forceinline__ float bf2f_lo(unsigned w) {
    union { unsigned u; float f; } c; c.u = w << 16;
    return c.f;
}
__device__ __forceinline__ float bf2f_hi(unsigned w) {
    union { unsigned u; float f; } c; c.u = w & 0xFFFF0000u;
    return c.f;
}

__device__ __forceinline__ short8 mk_s8(unsigned a, unsigned b, unsigned c, unsigned d) {
    union { unsigned u[4]; short8 s; } t;
    t.u[0] = a; t.u[1] = b; t.u[2] = c; t.u[3] = d;
    return t.s;
}

// ---------------------------------------------------------------------------
// Weight conversion, exact tile grid: dst[n][kperm(k)] = bf16(src[k][n]).
// ---------------------------------------------------------------------------
struct ConvSeg { const float* src; ushort_t* dst; int K; int N; int ntx; int base; int kperm; };
struct ConvArgs { ConvSeg s[14]; };

__global__ __launch_bounds__(256) void convert_kernel(ConvArgs args) {
    int bid = blockIdx.x;
    int si = 0;
#pragma unroll
    for (int i = 1; i < 14; i++) if (bid >= args.s[i].base) si = i;
    ConvSeg sg = args.s[si];
    int local = bid - sg.base;
    int ty = local / sg.ntx;
    int tx = local - ty * sg.ntx;
    int n0 = tx * 32, k0 = ty * 32;
    __shared__ float T[32][33];
    int tid = threadIdx.x;
    int tn = tid & 31, tk4 = tid >> 5;
#pragma unroll
    for (int i = 0; i < 4; i++) {
        int kl = tk4 + i * 8;
        float v = 0.0f;
        if (n0 + tn < sg.N) v = sg.src[(size_t)(k0 + kl) * sg.N + n0 + tn];
        T[kl][tn] = v;
    }
    __syncthreads();
    int tk = tid & 31, tn4 = tid >> 5;
    int tks = sg.kperm ? (((tk & 15) << 1) | ((tk >> 4) & 1)) : tk;
#pragma unroll
    for (int i = 0; i < 4; i++) {
        int nl = tn4 + i * 8;
        sg.dst[(size_t)(n0 + nl) * sg.K + k0 + tks] = f2bf(T[tk][nl]);
    }
}

// ---------------------------------------------------------------------------
// concat row [inter_e(256) | pat_e(64) | feat_e(64)] -> bf16 (plain layout)
// ---------------------------------------------------------------------------
__global__ __launch_bounds__(384) void concat_kernel(
    const int* __restrict__ interactions, const int* __restrict__ patterns,
    const float* __restrict__ ff, const float* __restrict__ inter_emb,
    const float* __restrict__ pattern_emb, const float* __restrict__ feat_W,
    const float* __restrict__ feat_b, ushort_t* __restrict__ out)
{
    int tok = blockIdx.x;
    int j = threadIdx.x;
    float v;
    if (j < 256) {
        v = inter_emb[(size_t)interactions[tok] * 256 + j];
    } else if (j < 320) {
        v = pattern_emb[patterns[tok] * 64 + (j - 256)];
    } else {
        int c = j - 320;
        float acc = feat_b[c];
#pragma unroll
        for (int f = 0; f < 8; f++) acc += ff[tok * 8 + f] * feat_W[f * 64 + c];
        v = acc;
    }
    out[(size_t)tok * 384 + j] = f2bf(v);
}

// ---------------------------------------------------------------------------
// ln_kernel v2 (vectorized): LayerNorm(x + r) in place. 16 rows/block.
// ---------------------------------------------------------------------------
__global__ __launch_bounds__(256) void ln_kernel(
    float* __restrict__ x, const ushort_t* __restrict__ r,
    const float* __restrict__ g, const float* __restrict__ b,
    ushort_t* __restrict__ xb)
{
    int t = threadIdx.x;
    int row = blockIdx.x * 16 + (t >> 4);
    int k = t & 15;
    int d0 = (k >> 1) * 32 + (k & 1) * 8;   // lower 8 at d0.., upper 8 at d0+16..
    int p0 = (k >> 1) * 32 + (k & 1) * 16;  // permuted byte-pair base
    size_t rowb = (size_t)row * DM;

    float4 xl0 = *(const float4*)&x[rowb + d0];
    float4 xl1 = *(const float4*)&x[rowb + d0 + 4];
    float4 xh0 = *(const float4*)&x[rowb + d0 + 16];
    float4 xh1 = *(const float4*)&x[rowb + d0 + 20];
    uint4 r0 = *(const uint4*)&r[rowb + p0];
    uint4 r1 = *(const uint4*)&r[rowb + p0 + 8];

    float vlo[8], vhi[8];
    unsigned rw[8] = {r0.x, r0.y, r0.z, r0.w, r1.x, r1.y, r1.z, r1.w};
    const float* xlp0 = (const float*)&xl0;
    const float* xlp1 = (const float*)&xl1;
    const float* xhp0 = (const float*)&xh0;
    const float* xhp1 = (const float*)&xh1;
#pragma unroll
    for (int i = 0; i < 4; i++) {
        vlo[i]     = xlp0[i] + bf2f_lo(rw[i]);
        vlo[4 + i] = xlp1[i] + bf2f_lo(rw[4 + i]);
        vhi[i]     = xhp0[i] + bf2f_hi(rw[i]);
        vhi[4 + i] = xhp1[i] + bf2f_hi(rw[4 + i]);
    }

    float s1 = 0.f, s2 = 0.f;
#pragma unroll
    for (int i = 0; i < 8; i++) {
        s1 += vlo[i] + vhi[i];
        s2 += vlo[i] * vlo[i] + vhi[i] * vhi[i];
    }
#pragma unroll
    for (int off = 1; off < 16; off <<= 1) {
        s1 += __shfl_xor(s1, off, 16);
        s2 += __shfl_xor(s2, off, 16);
    }
    float mean = s1 * (1.0f / 256.0f);
    float var = s2 * (1.0f / 256.0f) - mean * mean;
    float inv = rsqrtf(var + 1e-6f);

    float4 gl0 = *(const float4*)&g[d0];
    float4 gl1 = *(const float4*)&g[d0 + 4];
    float4 gh0 = *(const float4*)&g[d0 + 16];
    float4 gh1 = *(const float4*)&g[d0 + 20];
    float4 bl0 = *(const float4*)&b[d0];
    float4 bl1 = *(const float4*)&b[d0 + 4];
    float4 bh0 = *(const float4*)&b[d0 + 16];
    float4 bh1 = *(const float4*)&b[d0 + 20];
    const float* glp0 = (const float*)&gl0; const float* glp1 = (const float*)&gl1;
    const float* ghp0 = (const float*)&gh0; const float* ghp1 = (const float*)&gh1;
    const float* blp0 = (const float*)&bl0; const float* blp1 = (const float*)&bl1;
    const float* bhp0 = (const float*)&bh0; const float* bhp1 = (const float*)&bh1;

    float nlo[8], nhi[8];
#pragma unroll
    for (int i = 0; i < 4; i++) {
        nlo[i]     = glp0[i] * (vlo[i] - mean) * inv + blp0[i];
        nlo[4 + i] = glp1[i] * (vlo[4 + i] - mean) * inv + blp1[i];
        nhi[i]     = ghp0[i] * (vhi[i] - mean) * inv + bhp0[i];
        nhi[4 + i] = ghp1[i] * (vhi[4 + i] - mean) * inv + bhp1[i];
    }

    *(float4*)&x[rowb + d0]      = (float4){nlo[0], nlo[1], nlo[2], nlo[3]};
    *(float4*)&x[rowb + d0 + 4]  = (float4){nlo[4], nlo[5], nlo[6], nlo[7]};
    *(float4*)&x[rowb + d0 + 16] = (float4){nhi[0], nhi[1], nhi[2], nhi[3]};
    *(float4*)&x[rowb + d0 + 20] = (float4){nhi[4], nhi[5], nhi[6], nhi[7]};
    uint4 o0, o1;
    o0.x = pack_bf16(nlo[0], nhi[0]); o0.y = pack_bf16(nlo[1], nhi[1]);
    o0.z = pack_bf16(nlo[2], nhi[2]); o0.w = pack_bf16(nlo[3], nhi[3]);
    o1.x = pack_bf16(nlo[4], nhi[4]); o1.y = pack_bf16(nlo[5], nhi[5]);
    o1.z = pack_bf16(nlo[6], nhi[6]); o1.w = pack_bf16(nlo[7], nhi[7]);
    *(uint4*)&xb[rowb + p0]     = o0;
    *(uint4*)&xb[rowb + p0 + 8] = o1;
}

// ---------------------------------------------------------------------------
// gemm_inproj: gemm64 geometry (BM=64 BN=64 BK=32, 4 waves x 16x64),
// mode-4 epilogue hardcoded.
// ---------------------------------------------------------------------------
__global__ __launch_bounds__(256) void gemm_inproj(
    const ushort_t* __restrict__ A, const ushort_t* __restrict__ Bt,
    int N, int K,
    float* __restrict__ Cf, ushort_t* __restrict__ Cb,
    const float* __restrict__ b0,
    const float* __restrict__ ffg, const float* __restrict__ tW,
    const float* __restrict__ tb, const float* __restrict__ pW,
    const float* __restrict__ pb)
{
    __shared__ ushort_t As[2][64][40];
    __shared__ ushort_t Bs[2][64][40];
    int m0 = blockIdx.x * 64, n0 = blockIdx.y * 64;
    int tid = threadIdx.x;
    int wv = tid >> 6, lane = tid & 63;
    int quad = lane >> 4, l16 = lane & 15;
    int srow = tid >> 2, sc = (tid & 3) << 3;

    f32x4 acc[4];
#pragma unroll
    for (int j = 0; j < 4; j++) acc[j] = (f32x4){0.f, 0.f, 0.f, 0.f};

    uint4 pa = *(const uint4*)&A[(size_t)(m0 + srow) * K + sc];
    uint4 pbv = *(const uint4*)&Bt[(size_t)(n0 + srow) * K + sc];
    *(uint4*)&As[0][srow][sc] = pa;
    *(uint4*)&Bs[0][srow][sc] = pbv;

    int mrow = wv * 16;
    for (int k0 = 0; k0 < K; k0 += 32) {
        int cur = (k0 >> 5) & 1;
        __syncthreads();
        bool more = (k0 + 32 < K);
        if (more) {
            pa = *(const uint4*)&A[(size_t)(m0 + srow) * K + k0 + 32 + sc];
            pbv = *(const uint4*)&Bt[(size_t)(n0 + srow) * K + k0 + 32 + sc];
        }
        short8 af = *(const short8*)&As[cur][mrow + l16][quad * 8];
        short8 bf0 = *(const short8*)&Bs[cur][l16][quad * 8];
        short8 bf1 = *(const short8*)&Bs[cur][16 + l16][quad * 8];
        short8 bf2 = *(const short8*)&Bs[cur][32 + l16][quad * 8];
        short8 bf3 = *(const short8*)&Bs[cur][48 + l16][quad * 8];
        acc[0] = __builtin_amdgcn_mfma_f32_16x16x32_bf16(af, bf0, acc[0], 0, 0, 0);
        acc[1] = __builtin_amdgcn_mfma_f32_16x16x32_bf16(af, bf1, acc[1], 0, 0, 0);
        acc[2] = __builtin_amdgcn_mfma_f32_16x16x32_bf16(af, bf2, acc[2], 0, 0, 0);
        acc[3] = __builtin_amdgcn_mfma_f32_16x16x32_bf16(af, bf3, acc[3], 0, 0, 0);
        if (more) {
            *(uint4*)&As[cur ^ 1][srow][sc] = pa;
            *(uint4*)&Bs[cur ^ 1][srow][sc] = pbv;
        }
    }

#pragma unroll
    for (int r = 0; r < 4; r++) {
        int m = m0 + mrow + quad * 4 + r;
        int s = m & (SEQ - 1);
        float el = ffg[m * 8];
        float pos = (float)s * (1.0f / (float)SEQ);
#pragma unroll
        for (int nt = 0; nt < 4; nt += 2) {
            int nlo = n0 + nt * 16 + l16;
            int nhi = nlo + 16;
            float v0 = acc[nt][r] + b0[nlo] + tanhf(el * tW[nlo] + tb[nlo]) + pos * pW[nlo] + pb[nlo];
            float v1 = acc[nt + 1][r] + b0[nhi] + tanhf(el * tW[nhi] + tb[nhi]) + pos * pW[nhi] + pb[nhi];
            Cf[(size_t)m * N + nlo] = v0;
            Cf[(size_t)m * N + nhi] = v1;
            *(unsigned*)&Cb[(size_t)m * N + n0 + nt * 16 + 2 * l16] = pack_bf16(v0, v1);
        }
    }
}

// ---------------------------------------------------------------------------
// gemm_wo: gemm64 geometry, mode-5 epilogue hardcoded.
// ---------------------------------------------------------------------------
__global__ __launch_bounds__(256) void gemm_wo(
    const ushort_t* __restrict__ A, const ushort_t* __restrict__ Bt,
    int N, int K,
    ushort_t* __restrict__ Cb, const float* __restrict__ b0)
{
    __shared__ ushort_t As[2][64][40];
    __shared__ ushort_t Bs[2][64][40];
    int m0 = blockIdx.x * 64, n0 = blockIdx.y * 64;
    int tid = threadIdx.x;
    int wv = tid >> 6, lane = tid & 63;
    int quad = lane >> 4, l16 = lane & 15;
    int srow = tid >> 2, sc = (tid & 3) << 3;

    f32x4 acc[4];
#pragma unroll
    for (int j = 0; j < 4; j++) acc[j] = (f32x4){0.f, 0.f, 0.f, 0.f};

    uint4 pa = *(const uint4*)&A[(size_t)(m0 + srow) * K + sc];
    uint4 pbv = *(const uint4*)&Bt[(size_t)(n0 + srow) * K + sc];
    *(uint4*)&As[0][srow][sc] = pa;
    *(uint4*)&Bs[0][srow][sc] = pbv;

    int mrow = wv * 16;
    for (int k0 = 0; k0 < K; k0 += 32) {
        int cur = (k0 >> 5) & 1;
        __syncthreads();
        bool more = (k0 + 32 < K);
        if (more) {
            pa = *(const uint4*)&A[(size_t)(m0 + srow) * K + k0 + 32 + sc];
            pbv = *(const uint4*)&Bt[(size_t)(n0 + srow) * K + k0 + 32 + sc];
        }
        short8 af = *(const short8*)&As[cur][mrow + l16][quad * 8];
        short8 bf0 = *(const short8*)&Bs[cur][l16][quad * 8];
        short8 bf1 = *(const short8*)&Bs[cur][16 + l16][quad * 8];
        short8 bf2 = *(const short8*)&Bs[cur][32 + l16][quad * 8];
        short8 bf3 = *(const short8*)&Bs[cur][48 + l16][quad * 8];
        acc[0] = __builtin_amdgcn_mfma_f32_16x16x32_bf16(af, bf0, acc[0], 0, 0, 0);
        acc[1] = __builtin_amdgcn_mfma_f32_16x16x32_bf16(af, bf1, acc[1], 0, 0, 0);
        acc[2] = __builtin_amdgcn_mfma_f32_16x16x32_bf16(af, bf2, acc[2], 0, 0, 0);
        acc[3] = __builtin_amdgcn_mfma_f32_16x16x32_bf16(af, bf3, acc[3], 0, 0, 0);
        if (more) {
            *(uint4*)&As[cur ^ 1][srow][sc] = pa;
            *(uint4*)&Bs[cur ^ 1][srow][sc] = pbv;
        }
    }

#pragma unroll
    for (int r = 0; r < 4; r++) {
        int m = m0 + mrow + quad * 4 + r;
#pragma unroll
        for (int nt = 0; nt < 4; nt += 2) {
            int nlo = n0 + nt * 16 + l16;
            float v0 = acc[nt][r] + b0[nlo];
            float v1 = acc[nt + 1][r] + b0[nlo + 16];
            *(unsigned*)&Cb[(size_t)m * N + n0 + nt * 16 + 2 * l16] = pack_bf16(v0, v1);
        }
    }
}

// ---------------------------------------------------------------------------
// gemm_ffn2: gemm_db geometry (BM=128 BN=64, 8 mfma/iter/wave) for FFN2
// (M=8192, N=256, K=1024), bias-only packed-bf16 epilogue. Grid (64,4).
// ---------------------------------------------------------------------------
__global__ __launch_bounds__(256) void gemm_ffn2(
    const ushort_t* __restrict__ A, const ushort_t* __restrict__ Bt,
    int N, int K,
    ushort_t* __restrict__ Cb, const float* __restrict__ b0)
{
    __shared__ ushort_t As[2][128][40];
    __shared__ ushort_t Bs[2][64][40];
    int m0 = blockIdx.x * 128, n0 = blockIdx.y * 64;
    int tid = threadIdx.x;
    int wv = tid >> 6, lane = tid & 63;
    int quad = lane >> 4, l16 = lane & 15;
    int srow = tid >> 2, sc = (tid & 3) << 3;

    f32x4 acc[2][4];
#pragma unroll
    for (int i = 0; i < 2; i++)
#pragma unroll
        for (int j = 0; j < 4; j++) acc[i][j] = (f32x4){0.f, 0.f, 0.f, 0.f};

    uint4 pa0 = *(const uint4*)&A[(size_t)(m0 + srow) * K + sc];
    uint4 pa1 = *(const uint4*)&A[(size_t)(m0 + 64 + srow) * K + sc];
    uint4 pbb = *(const uint4*)&Bt[(size_t)(n0 + srow) * K + sc];
    *(uint4*)&As[0][srow][sc] = pa0;
    *(uint4*)&As[0][64 + srow][sc] = pa1;
    *(uint4*)&Bs[0][srow][sc] = pbb;

    int msub = wv * 32;
    for (int k0 = 0; k0 < K; k0 += 32) {
        int cur = (k0 >> 5) & 1;
        __syncthreads();
        bool more = (k0 + 32 < K);
        if (more) {
            pa0 = *(const uint4*)&A[(size_t)(m0 + srow) * K + k0 + 32 + sc];
            pa1 = *(const uint4*)&A[(size_t)(m0 + 64 + srow) * K + k0 + 32 + sc];
            pbb = *(const uint4*)&Bt[(size_t)(n0 + srow) * K + k0 + 32 + sc];
        }
        short8 af0 = *(const short8*)&As[cur][msub + l16][quad * 8];
        short8 af1 = *(const short8*)&As[cur][msub + 16 + l16][quad * 8];
        short8 bf0 = *(const short8*)&Bs[cur][l16][quad * 8];
        short8 bf1 = *(const short8*)&Bs[cur][16 + l16][quad * 8];
        short8 bf2 = *(const short8*)&Bs[cur][32 + l16][quad * 8];
        short8 bf3 = *(const short8*)&Bs[cur][48 + l16][quad * 8];
        acc[0][0] = __builtin_amdgcn_mfma_f32_16x16x32_bf16(af0, bf0, acc[0][0], 0, 0, 0);
        acc[0][1] = __builtin_amdgcn_mfma_f32_16x16x32_bf16(af0, bf1, acc[0][1], 0, 0, 0);
        acc[0][2] = __builtin_amdgcn_mfma_f32_16x16x32_bf16(af0, bf2, acc[0][2], 0, 0, 0);
        acc[0][3] = __builtin_amdgcn_mfma_f32_16x16x32_bf16(af0, bf3, acc[0][3], 0, 0, 0);
        acc[1][0] = __builtin_amdgcn_mfma_f32_16x16x32_bf16(af1, bf0, acc[1][0], 0, 0, 0);
        acc[1][1] = __builtin_amdgcn_mfma_f32_16x16x32_bf16(af1, bf1, acc[1][1], 0, 0, 0);
        acc[1][2] = __builtin_amdgcn_mfma_f32_16x16x32_bf16(af1, bf2, acc[1][2], 0, 0, 0);
        acc[1][3] = __builtin_amdgcn_mfma_f32_16x16x32_bf16(af1, bf3, acc[1][3], 0, 0, 0);
        if (more) {
            *(uint4*)&As[cur ^ 1][srow][sc] = pa0;
            *(uint4*)&As[cur ^ 1][64 + srow][sc] = pa1;
            *(uint4*)&Bs[cur ^ 1][srow][sc] = pbb;
        }
    }

#pragma unroll
    for (int mt = 0; mt < 2; mt++) {
#pragma unroll
        for (int nt = 0; nt < 4; nt += 2) {
            int nlo = n0 + nt * 16 + l16;
#pragma unroll
            for (int r = 0; r < 4; r++) {
                int m = m0 + msub + mt * 16 + quad * 4 + r;
                float t0 = acc[mt][nt][r] + b0[nlo];
                float t1 = acc[mt][nt + 1][r] + b0[nlo + 16];
                *(unsigned*)&Cb[(size_t)m * N + n0 + nt * 16 + 2 * l16] = pack_bf16(t0, t1);
            }
        }
    }
}

// ---------------------------------------------------------------------------
// gemm_db: BM=128 BN=64 BK=32, double-buffered (1 barrier/iter).
// mode 1: gelu -> packed bf16
// mode 2: QKV epilogue
// ---------------------------------------------------------------------------
__global__ __launch_bounds__(256) void gemm_db(
    const ushort_t* __restrict__ A, const ushort_t* __restrict__ Bt,
    int M, int N, int K, int mode,
    ushort_t* __restrict__ Cb, ushort_t* __restrict__ Ck, ushort_t* __restrict__ Cv,
    const float* __restrict__ b0, const float* __restrict__ b1,
    const float* __restrict__ b2)
{
    __shared__ ushort_t As[2][128][40];
    __shared__ ushort_t Bs[2][64][40];
    int m0 = blockIdx.x * 128, n0 = blockIdx.y * 64;
    int tid = threadIdx.x;
    int wv = tid >> 6, lane = tid & 63;
    int quad = lane >> 4, l16 = lane & 15;
    int srow = tid >> 2, sc = (tid & 3) << 3;

    f32x4 acc[2][4];
#pragma unroll
    for (int i = 0; i < 2; i++)
#pragma unroll
        for (int j = 0; j < 4; j++) acc[i][j] = (f32x4){0.f, 0.f, 0.f, 0.f};

    uint4 pa0 = *(const uint4*)&A[(size_t)(m0 + srow) * K + sc];
    uint4 pa1 = *(const uint4*)&A[(size_t)(m0 + 64 + srow) * K + sc];
    uint4 pbb = *(const uint4*)&Bt[(size_t)(n0 + srow) * K + sc];
    *(uint4*)&As[0][srow][sc] = pa0;
    *(uint4*)&As[0][64 + srow][sc] = pa1;
    *(uint4*)&Bs[0][srow][sc] = pbb;

    int msub = wv * 32;
    for (int k0 = 0; k0 < K; k0 += 32) {
        int cur = (k0 >> 5) & 1;
        __syncthreads();
        bool more = (k0 + 32 < K);
        if (more) {
            pa0 = *(const uint4*)&A[(size_t)(m0 + srow) * K + k0 + 32 + sc];
            pa1 = *(const uint4*)&A[(size_t)(m0 + 64 + srow) * K + k0 + 32 + sc];
            pbb = *(const uint4*)&Bt[(size_t)(n0 + srow) * K + k0 + 32 + sc];
        }
        short8 af0 = *(const short8*)&As[cur][msub + l16][quad * 8];
        short8 af1 = *(const short8*)&As[cur][msub + 16 + l16][quad * 8];
        short8 bf0 = *(const short8*)&Bs[cur][l16][quad * 8];
        short8 bf1 = *(const short8*)&Bs[cur][16 + l16][quad * 8];
        short8 bf2 = *(const short8*)&Bs[cur][32 + l16][quad * 8];
        short8 bf3 = *(const short8*)&Bs[cur][48 + l16][quad * 8];
        acc[0][0] = __builtin_amdgcn_mfma_f32_16x16x32_bf16(af0, bf0, acc[0][0], 0, 0, 0);
        acc[0][1] = __builtin_amdgcn_mfma_f32_16x16x32_bf16(af0, bf1, acc[0][1], 0, 0, 0);
        acc[0][2] = __builtin_amdgcn_mfma_f32_16x16x32_bf16(af0, bf2, acc[0][2], 0, 0, 0);
        acc[0][3] = __builtin_amdgcn_mfma_f32_16x16x32_bf16(af0, bf3, acc[0][3], 0, 0, 0);
        acc[1][0] = __builtin_amdgcn_mfma_f32_16x16x32_bf16(af1, bf0, acc[1][0], 0, 0, 0);
        acc[1][1] = __builtin_amdgcn_mfma_f32_16x16x32_bf16(af1, bf1, acc[1][1], 0, 0, 0);
        acc[1][2] = __builtin_amdgcn_mfma_f32_16x16x32_bf16(af1, bf2, acc[1][2], 0, 0, 0);
        acc[1][3] = __builtin_amdgcn_mfma_f32_16x16x32_bf16(af1, bf3, acc[1][3], 0, 0, 0);
        if (more) {
            *(uint4*)&As[cur ^ 1][srow][sc] = pa0;
            *(uint4*)&As[cur ^ 1][64 + srow][sc] = pa1;
            *(uint4*)&Bs[cur ^ 1][srow][sc] = pbb;
        }
    }

#pragma unroll
    for (int mt = 0; mt < 2; mt++) {
#pragma unroll
        for (int nt = 0; nt < 4; nt += 2) {
            int nlo = n0 + nt * 16 + l16;
#pragma unroll
            for (int r = 0; r < 4; r++) {
                int m = m0 + msub + mt * 16 + quad * 4 + r;
                float vlo = acc[mt][nt][r];
                float vhi = acc[mt][nt + 1][r];
                if (mode == 1) {
                    float t0 = vlo + b0[nlo];
                    float t1 = vhi + b0[nlo + 16];
                    t0 = 0.5f * t0 * (1.0f + erff(t0 * 0.70710678118654752f));
                    t1 = 0.5f * t1 * (1.0f + erff(t1 * 0.70710678118654752f));
                    *(unsigned*)&Cb[(size_t)m * N + n0 + nt * 16 + 2 * l16] = pack_bf16(t0, t1);
                } else {
                    int which = nlo >> 8, idx = nlo & 255;
                    int hh = idx >> 5;          // d == l16, partner d+16 same head
                    int s = m & (SEQ - 1), b = m >> 11;
                    if (which == 0) {
                        float q0 = (vlo + b0[idx]) * QPRE;
                        float q1 = (vhi + b0[idx + 16]) * QPRE;
                        *(unsigned*)&Cb[(((size_t)(b * NHD + hh)) * SEQ + s) * DHD + 2 * l16] = pack_bf16(q0, q1);
                    } else if (which == 1) {
                        float k0v = vlo + b1[idx];
                        float k1v = vhi + b1[idx + 16];
                        *(unsigned*)&Ck[(((size_t)(b * NHD + hh)) * SEQ + s) * DHD + 2 * l16] = pack_bf16(k0v, k1v);
                    } else {
                        Cv[(((size_t)(b * NHD + hh)) * DHD + l16) * SEQ + s] = f2bf(vlo + b2[idx]);
                        Cv[(((size_t)(b * NHD + hh)) * DHD + l16 + 16) * SEQ + s] = f2bf(vhi + b2[idx + 16]);
                    }
                }
            }
        }
    }
}

// ---------------------------------------------------------------------------
// gemm_out: BM=128 BN=128 BK=32, double-buffered. fp32 + bias, n < Nreal.
// ---------------------------------------------------------------------------
__global__ __launch_bounds__(256) void gemm_out(
    const ushort_t* __restrict__ A, const ushort_t* __restrict__ Bt,
    int M, int N, int K,
    float* __restrict__ Cf, const float* __restrict__ b0, int Nreal)
{
    __shared__ ushort_t As[2][128][40];
    __shared__ ushort_t Bs[2][128][40];
    int m0 = blockIdx.x * 128, n0 = blockIdx.y * 128;
    int tid = threadIdx.x;
    int wv = tid >> 6, lane = tid & 63;
    int quad = lane >> 4, l16 = lane & 15;
    int wm = (wv >> 1) * 64, wn = (wv & 1) * 64;
    int srow = tid >> 1, sc = (tid & 1) << 4;

    f32x4 acc[4][4];
#pragma unroll
    for (int i = 0; i < 4; i++)
#pragma unroll
        for (int j = 0; j < 4; j++) acc[i][j] = (f32x4){0.f, 0.f, 0.f, 0.f};

    uint4 pa0 = *(const uint4*)&A[(size_t)(m0 + srow) * K + sc];
    uint4 pa1 = *(const uint4*)&A[(size_t)(m0 + srow) * K + sc + 8];
    uint4 pb0 = *(const uint4*)&Bt[(size_t)(n0 + srow) * K + sc];
    uint4 pb1 = *(const uint4*)&Bt[(size_t)(n0 + srow) * K + sc + 8];
    *(uint4*)&As[0][srow][sc] = pa0;
    *(uint4*)&As[0][srow][sc + 8] = pa1;
    *(uint4*)&Bs[0][srow][sc] = pb0;
    *(uint4*)&Bs[0][srow][sc + 8] = pb1;

    for (int k0 = 0; k0 < K; k0 += 32) {
        int cur = (k0 >> 5) & 1;
        __syncthreads();
        bool more = (k0 + 32 < K);
        if (more) {
            pa0 = *(const uint4*)&A[(size_t)(m0 + srow) * K + k0 + 32 + sc];
            pa1 = *(const uint4*)&A[(size_t)(m0 + srow) * K + k0 + 32 + sc + 8];
            pb0 = *(const uint4*)&Bt[(size_t)(n0 + srow) * K + k0 + 32 + sc];
            pb1 = *(const uint4*)&Bt[(size_t)(n0 + srow) * K + k0 + 32 + sc + 8];
        }
        short8 af[4], bf[4];
#pragma unroll
        for (int i = 0; i < 4; i++) {
            af[i] = *(const short8*)&As[cur][wm + i * 16 + l16][quad * 8];
            bf[i] = *(const short8*)&Bs[cur][wn + i * 16 + l16][quad * 8];
        }
#pragma unroll
        for (int i = 0; i < 4; i++)
#pragma unroll
            for (int j = 0; j < 4; j++)
                acc[i][j] = __builtin_amdgcn_mfma_f32_16x16x32_bf16(af[i], bf[j], acc[i][j], 0, 0, 0);
        if (more) {
            *(uint4*)&As[cur ^ 1][srow][sc] = pa0;
            *(uint4*)&As[cur ^ 1][srow][sc + 8] = pa1;
            *(uint4*)&Bs[cur ^ 1][srow][sc] = pb0;
            *(uint4*)&Bs[cur ^ 1][srow][sc + 8] = pb1;
        }
    }

#pragma unroll
    for (int i = 0; i < 4; i++) {
#pragma unroll
        for (int j = 0; j < 4; j++) {
            int n = n0 + wn + j * 16 + l16;
            if (n < Nreal) {
#pragma unroll
                for (int r = 0; r < 4; r++) {
                    int m = m0 + wm + i * 16 + quad * 4 + r;
                    Cf[(size_t)m * Nreal + n] = acc[i][j][r] + b0[n];
                }
            }
        }
    }
}

// ---------------------------------------------------------------------------
// MFMA flash attention v5 (v4 + MFMA-computed denominators):
//  - denominator = mfma(pf, ones_bf16, den): Sum_k P[q][k] lands at
//    lane(quad,l16) reg r as den-of-q-row (quad*4+r), replicated over l16 --
//    EXACTLY the (qr+r) layout the epilogue consumes from LsB. Removes the
//    7-add tree per tile in-loop and the 4x shfl_xor epilogue reduce.
//  - denominator now sums the SAME bf16-rounded P as the PV numerator
//    (more consistent softmax normalization).
//  - probe removed (R10 verdict: small-GEMM cost was positional; kernels
//    are ~5us intrinsic; ~207us of total is harness re-poison fills).
// ---------------------------------------------------------------------------
__global__ __launch_bounds__(256) void attn_mfma(
    const ushort_t* __restrict__ qb, const ushort_t* __restrict__ kb,
    const ushort_t* __restrict__ vtb, const float* __restrict__ kp,
    const float* __restrict__ ka, ushort_t* __restrict__ ob)
{
    // gid = (hb>>3)*512 + pj*8 + (hb&7)  (bijective over 2048)
    int gid = blockIdx.x;
    int hb = ((gid >> 9) << 3) | (gid & 7);
    int pj = (gid >> 3) & 63;
    int b = hb >> 3, h = hb & 7;

    int tid = threadIdx.x, wv = tid >> 6, lane = tid & 63;
    int quad = lane >> 4, l16 = lane & 15;

    __shared__ float tabs[2112];
    __shared__ __align__(16) float ShA[2560];   // O-combine, stride 20
    __shared__ float LsB[128];                  // per-wave denominators

    float p = log1pf(__expf(kp[h]));
    float a = log1pf(__expf(ka[h]));
    for (int i = tid; i < 2112; i += 256) {
        float w = 0.0f;
        if (i >= 64) w = fexp2(-p * __log2f(fmaf(a, (float)(i - 64), 1.0f)));
        tabs[i] = w;
    }
    __syncthreads();

    int bh = b * NHD + h;
    const ushort_t* Qh = qb + (size_t)bh * SEQ * DHD;
    const ushort_t* Kh = kb + (size_t)bh * SEQ * DHD;
    const ushort_t* Vh = vtb + (size_t)bh * DHD * SEQ;

    int tlo = pj, thi = 127 - pj;
    int qlo0 = tlo * 16, qhi0 = thi * 16;

    short8 qfl = *(const short8*)&Qh[(qlo0 + l16) * DHD + quad * 8];
    short8 qfh = *(const short8*)&Qh[(qhi0 + l16) * DHD + quad * 8];
    f32x4 ol0 = (f32x4){0.f,0.f,0.f,0.f}, ol1 = (f32x4){0.f,0.f,0.f,0.f};
    f32x4 oh0 = (f32x4){0.f,0.f,0.f,0.f}, oh1 = (f32x4){0.f,0.f,0.f,0.f};
    f32x4 dh_acc = (f32x4){0.f,0.f,0.f,0.f}, dl_acc = (f32x4){0.f,0.f,0.f,0.f};
    // all-ones bf16 B-fragment (1.0 = 0x3F80)
    const short8 onesf = mk_s8(0x3F803F80u, 0x3F803F80u, 0x3F803F80u, 0x3F803F80u);

    int nch_hi = (thi + 2) >> 1;     // >= 33, so every wave gets hi work
    int nch_lo = (tlo + 2) >> 1;     // >= 1
    // permuted K row offset: l16 -> {0-3,8-11,16-19,24-27}
    int krow = ((l16 >> 2) << 3) | (l16 & 3);
    int tb_h = qhi0 + l16 + 64 - 8 * quad;
    int tb_l = qlo0 + l16 + 64 - 8 * quad;

    int ch = wv;
    short8 kf0n, kf1n;
    {
        int k0 = ch * 32;
        kf0n = *(const short8*)&Kh[(k0 + krow) * DHD + quad * 8];
        kf1n = *(const short8*)&Kh[(k0 + 4 + krow) * DHD + quad * 8];
    }

    for (; ch < nch_hi; ch += 4) {
        int k0 = ch * 32;
        short8 kf0 = kf0n, kf1 = kf1n;
        short8 vf0 = *(const short8*)&Vh[l16 * SEQ + k0 + quad * 8];
        short8 vf1 = *(const short8*)&Vh[(16 + l16) * SEQ + k0 + quad * 8];
        int chn = ch + 4;
        if (chn < nch_hi) {
            int kn = chn * 32;
            kf0n = *(const short8*)&Kh[(kn + krow) * DHD + quad * 8];
            kf1n = *(const short8*)&Kh[(kn + 4 + krow) * DHD + quad * 8];
        }
        f32x4 z = (f32x4){0.f,0.f,0.f,0.f};

        // scores: s0[r] = S[k0+8q+r][q=l16], s1[r] = S[k0+8q+4+r][q=l16]
        f32x4 s0 = __builtin_amdgcn_mfma_f32_16x16x32_bf16(kf0, qfh, z, 0, 0, 0);
        f32x4 s1 = __builtin_amdgcn_mfma_f32_16x16x32_bf16(kf1, qfh, z, 0, 0, 0);
        {
            const float* tp = &tabs[tb_h - k0];
            float e0 = fexp2(s0[0]) * tp[0];
            float e1 = fexp2(s0[1]) * tp[-1];
            float e2 = fexp2(s0[2]) * tp[-2];
            float e3 = fexp2(s0[3]) * tp[-3];
            unsigned p0 = pack_bf16(e0, e1);
            unsigned p1 = pack_bf16(e2, e3);
            float f0 = fexp2(s1[0]) * tp[-4];
            float f1 = fexp2(s1[1]) * tp[-5];
            float f2 = fexp2(s1[2]) * tp[-6];
            float f3 = fexp2(s1[3]) * tp[-7];
            unsigned p2 = pack_bf16(f0, f1);
            unsigned p3 = pack_bf16(f2, f3);
            short8 pf = mk_s8(p0, p1, p2, p3);
            oh0 = __builtin_amdgcn_mfma_f32_16x16x32_bf16(pf, vf0, oh0, 0, 0, 0);
            oh1 = __builtin_amdgcn_mfma_f32_16x16x32_bf16(pf, vf1, oh1, 0, 0, 0);
            dh_acc = __builtin_amdgcn_mfma_f32_16x16x32_bf16(pf, onesf, dh_acc, 0, 0, 0);
        }
        if (ch < nch_lo) {
            f32x4 t0 = __builtin_amdgcn_mfma_f32_16x16x32_bf16(kf0, qfl, z, 0, 0, 0);
            f32x4 t1 = __builtin_amdgcn_mfma_f32_16x16x32_bf16(kf1, qfl, z, 0, 0, 0);
            const float* tq = &tabs[tb_l - k0];
            float e0 = fexp2(t0[0]) * tq[0];
            float e1 = fexp2(t0[1]) * tq[-1];
            float e2 = fexp2(t0[2]) * tq[-2];
            float e3 = fexp2(t0[3]) * tq[-3];
            unsigned p0 = pack_bf16(e0, e1);
            unsigned p1 = pack_bf16(e2, e3);
            float f0 = fexp2(t1[0]) * tq[-4];
            float f1 = fexp2(t1[1]) * tq[-5];
            float f2 = fexp2(t1[2]) * tq[-6];
            float f3 = fexp2(t1[3]) * tq[-7];
            unsigned p2 = pack_bf16(f0, f1);
            unsigned p3 = pack_bf16(f2, f3);
            short8 pf = mk_s8(p0, p1, p2, p3);
            ol0 = __builtin_amdgcn_mfma_f32_16x16x32_bf16(pf, vf0, ol0, 0, 0, 0);
            ol1 = __builtin_amdgcn_mfma_f32_16x16x32_bf16(pf, vf1, ol1, 0, 0, 0);
            dl_acc = __builtin_amdgcn_mfma_f32_16x16x32_bf16(pf, onesf, dl_acc, 0, 0, 0);
        }
    }

    // ---- per-wave denominators (already per-q in (quad*4+r) layout,
    //      replicated across l16) -> LsB[wv*32 + q]
    if (l16 == 0) {
#pragma unroll
        for (int r = 0; r < 4; r++) {
            LsB[wv * 32 + quad * 4 + r] = dh_acc[r];
            LsB[wv * 32 + 16 + quad * 4 + r] = dl_acc[r];
        }
    }

    // ---- cross-wave O combine tree
    float* cp = &ShA[((wv >> 1) * 64 + lane) * 20];
    if (wv & 1) {
        *(float4*)&cp[0]  = (float4){oh0[0], oh0[1], oh0[2], oh0[3]};
        *(float4*)&cp[4]  = (float4){oh1[0], oh1[1], oh1[2], oh1[3]};
        *(float4*)&cp[8]  = (float4){ol0[0], ol0[1], ol0[2], ol0[3]};
        *(float4*)&cp[12] = (float4){ol1[0], ol1[1], ol1[2], ol1[3]};
    }
    __syncthreads();
    if (!(wv & 1)) {
#pragma unroll
        for (int i = 0; i < 4; i++) {
            oh0[i] += cp[i];      oh1[i] += cp[4 + i];
            ol0[i] += cp[8 + i];  ol1[i] += cp[12 + i];
        }
    }
    __syncthreads();
    if (wv == 2) {
        float* c0 = &ShA[lane * 20];
        *(float4*)&c0[0]  = (float4){oh0[0], oh0[1], oh0[2], oh0[3]};
        *(float4*)&c0[4]  = (float4){oh1[0], oh1[1], oh1[2], oh1[3]};
        *(float4*)&c0[8]  = (float4){ol0[0], ol0[1], ol0[2], ol0[3]};
        *(float4*)&c0[12] = (float4){ol1[0], ol1[1], ol1[2], ol1[3]};
    }
    __syncthreads();
    if (wv == 0) {
        const float* c0 = &ShA[lane * 20];
#pragma unroll
        for (int i = 0; i < 4; i++) {
            oh0[i] += c0[i];      oh1[i] += c0[4 + i];
            ol0[i] += c0[8 + i];  ol1[i] += c0[12 + i];
        }
        int qr = quad * 4;
        int qsrh = qhi0 + qr, qsrl = qlo0 + qr;
#pragma unroll
        for (int r = 0; r < 4; r++) {
            float dh = (LsB[qr + r] + LsB[32 + qr + r]) + (LsB[64 + qr + r] + LsB[96 + qr + r]);
            float dl = (LsB[16 + qr + r] + LsB[48 + qr + r]) + (LsB[80 + qr + r] + LsB[112 + qr + r]);
            float rh = 1.0f / dh;
            float rl = 1.0f / dl;
            size_t bh_ = ((size_t)(b * SEQ + qsrh + r)) * DM + h * DHD;
            size_t bl_ = ((size_t)(b * SEQ + qsrl + r)) * DM + h * DHD;
            *(unsigned*)&ob[bh_ + 2 * l16] = pack_bf16(oh0[r] * rh, oh1[r] * rh);
            *(unsigned*)&ob[bl_ + 2 * l16] = pack_bf16(ol0[r] * rl, ol1[r] * rl);
        }
    }
}

// ---------------------------------------------------------------------------
extern "C" void kernel_launch(void* const* d_in, const int* in_sizes, int n_in,
                              void* d_out, int out_size, void* d_ws, size_t ws_size,
                              hipStream_t stream) {
    const int*   interactions = (const int*)d_in[0];
    const int*   patterns     = (const int*)d_in[1];
    const float* ff           = (const float*)d_in[2];
    const float* inter_emb    = (const float*)d_in[3];
    const float* pattern_emb  = (const float*)d_in[4];
    const float* feat_W       = (const float*)d_in[5];
    const float* feat_b       = (const float*)d_in[6];
    const float* in_W         = (const float*)d_in[7];
    const float* in_b         = (const float*)d_in[8];
    const float* time_W       = (const float*)d_in[9];
    const float* time_b       = (const float*)d_in[10];
    const float* pos_W        = (const float*)d_in[11];
    const float* pos_b        = (const float*)d_in[12];
    const float* Wq           = (const float*)d_in[13];
    const float* bq           = (const float*)d_in[14];
    const float* Wk           = (const float*)d_in[15];
    const float* bk           = (const float*)d_in[16];
    const float* Wv           = (const float*)d_in[17];
    const float* bv           = (const float*)d_in[18];
    const float* Wo           = (const float*)d_in[19];
    const float* bo           = (const float*)d_in[20];
    const float* kerple_p     = (const float*)d_in[21];
    const float* kerple_a     = (const float*)d_in[22];
    const float* ln1_g        = (const float*)d_in[23];
    const float* ln1_b        = (const float*)d_in[24];
    const float* ln2_g        = (const float*)d_in[25];
    const float* ln2_b        = (const float*)d_in[26];
    const float* ffn_W1       = (const float*)d_in[27];
    const float* ffn_b1       = (const float*)d_in[28];
    const float* ffn_W2       = (const float*)d_in[29];
    const float* ffn_b2       = (const float*)d_in[30];
    const float* out_W        = (const float*)d_in[31];
    const float* out_b        = (const float*)d_in[32];
    float* out = (float*)d_out;

    // ---- workspace layout (bytes) ----
    char* wsb = (char*)d_ws;
    const size_t MB = 1024 * 1024;
    float*    x    = (float*)(wsb + 0);          //  8 MB fp32 activations (plain)
    ushort_t* tmpb = (ushort_t*)(wsb + 8  * MB); //  4 MB bf16 residual (perm)
    ushort_t* xb   = (ushort_t*)(wsb + 16 * MB); //  4 MB bf16 x copy (perm)
    ushort_t* qbuf = (ushort_t*)(wsb + 20 * MB); //  4 MB Q (B,H,S,DH) d-perm, pre-scaled
    ushort_t* kbuf = (ushort_t*)(wsb + 24 * MB); //  4 MB K (B,H,S,DH) d-perm
    ushort_t* vtbf = (ushort_t*)(wsb + 28 * MB); //  4 MB V^T (B,H,DH,S) plain
    ushort_t* shrd = (ushort_t*)(wsb + 32 * MB); // 16 MB: cbuf / o_bf / h_bf
    ushort_t* cbuf = shrd;
    ushort_t* o_bf = shrd;
    ushort_t* h_bf = shrd;
    char* wp = wsb + 48 * MB;
    ushort_t* inWt  = (ushort_t*)wp;  wp += 256  * 384 * 2;
    ushort_t* qkvWt = (ushort_t*)wp;  wp += 2 * 768 * 256 * 2;
    ushort_t* WoT   = (ushort_t*)wp;  wp += 2 * 256 * 256 * 2;
    ushort_t* W1T   = (ushort_t*)wp;  wp += 2 * 1024 * 256 * 2;
    ushort_t* W2T   = (ushort_t*)wp;  wp += 2 * 256 * 1024 * 2;
    ushort_t* outWt = (ushort_t*)wp;  wp += 2048 * 256 * 2;

    // ---- weight conversion ----
    ConvArgs ca;
    int D2 = 256 * 256;
    int base = 0, ib = 0;
    auto addseg = [&](const float* src, ushort_t* dst, int K, int N, int Npad, int kp) {
        ca.s[ib].src = src; ca.s[ib].dst = dst; ca.s[ib].K = K; ca.s[ib].N = N;
        ca.s[ib].ntx = Npad / 32; ca.s[ib].base = base; ca.s[ib].kperm = kp;
        base += (Npad / 32) * (K / 32); ib++;
    };
    addseg(in_W,            inWt,           384,  256,  256,  0);
    addseg(Wq,              qkvWt,          256,  256,  256,  1);
    addseg(Wk,              qkvWt + 1 * D2, 256,  256,  256,  1);
    addseg(Wv,              qkvWt + 2 * D2, 256,  256,  256,  1);
    addseg(Wq + D2,         qkvWt + 3 * D2, 256,  256,  256,  1);
    addseg(Wk + D2,         qkvWt + 4 * D2, 256,  256,  256,  1);
    addseg(Wv + D2,         qkvWt + 5 * D2, 256,  256,  256,  1);
    addseg(Wo,              WoT,            256,  256,  256,  1);
    addseg(Wo + D2,         WoT + D2,       256,  256,  256,  1);
    addseg(ffn_W1,          W1T,            256,  1024, 1024, 1);
    addseg(ffn_W1 + 4 * D2, W1T + 4 * D2,   256,  1024, 1024, 1);
    addseg(ffn_W2,          W2T,            1024, 256,  256,  1);
    addseg(ffn_W2 + 4 * D2, W2T + 4 * D2,   1024, 256,  256,  1);
    addseg(out_W,           outWt,          256,  2000, 2048, 1);
    convert_kernel<<<base, 256, 0, stream>>>(ca);

    // ---- input projection (+ fused time/pos encodings) ----
    concat_kernel<<<NTOK, 384, 0, stream>>>(interactions, patterns, ff,
                                            inter_emb, pattern_emb, feat_W, feat_b, cbuf);
    gemm_inproj<<<dim3(128, 4), 256, 0, stream>>>(cbuf, inWt, 256, 384,
                                                  x, xb, in_b, ff, time_W, time_b, pos_W, pos_b);

    for (int l = 0; l < 2; l++) {
        gemm_db<<<dim3(64, 12), 256, 0, stream>>>(
            xb, qkvWt + (size_t)l * 768 * 256, NTOK, 768, 256, 2,
            qbuf, kbuf, vtbf, bq + l * 256, bk + l * 256, bv + l * 256);
        attn_mfma<<<2048, 256, 0, stream>>>(
            qbuf, kbuf, vtbf, kerple_p + l * NHD, kerple_a + l * NHD, o_bf);
        gemm_wo<<<dim3(128, 4), 256, 0, stream>>>(
            o_bf, WoT + (size_t)l * D2, 256, 256, tmpb, bo + l * 256);
        ln_kernel<<<NTOK / 16, 256, 0, stream>>>(x, tmpb, ln1_g + l * 256, ln1_b + l * 256, xb);
        gemm_db<<<dim3(64, 16), 256, 0, stream>>>(
            xb, W1T + (size_t)l * 4 * D2, NTOK, 1024, 256, 1,
            h_bf, nullptr, nullptr, ffn_b1 + l * 1024, nullptr, nullptr);
        gemm_ffn2<<<dim3(64, 4), 256, 0, stream>>>(
            h_bf, W2T + (size_t)l * 4 * D2, 256, 1024, tmpb, ffn_b2 + l * 256);
        ln_kernel<<<NTOK / 16, 256, 0, stream>>>(x, tmpb, ln2_g + l * 256, ln2_b + l * 256, xb);
    }

    // ---- output projection (N=2048 padded, guard to 2000, plain fp32 out) ----
    gemm_out<<<dim3(64, 16), 256, 0, stream>>>(
        xb, outWt, NTOK, 2048, 256, out, out_b, NSKC);
}